// Round 1
// baseline (30603.922 us; speedup 1.0000x reference)
//
#include <hip/hip_runtime.h>

#define USERN 50000
#define ITEMN 20000
#define NN    70000
#define DTOT  256        // 4 branches x 64
#define LAMv  0.2f
#define E_MAINN  2000000
#define E_MODALN 1000000

// ---------------- dense projection GEMM: F[:,blkA*64..]=A@W0+b0, F[:,blkB*64..]=A@W1+b1 ----
#define BM 64
#define BN 128
#define BK 32

__global__ __launch_bounds__(256) void gemm_proj(
    const float* __restrict__ A, int M, int K,
    const float* __restrict__ W0, const float* __restrict__ W1,
    const float* __restrict__ b0, const float* __restrict__ b1,
    float* __restrict__ F, int blkA, int blkB)
{
    __shared__ float As[BK][BM];   // transposed A tile
    __shared__ float Ws[BK][BN];   // [k][col], cols 0-63 from W0, 64-127 from W1
    const int tid  = threadIdx.x;
    const int row0 = blockIdx.x * BM;
    const int cx = tid & 15, ry = tid >> 4;          // thread computes rows ry*4..+3, cols cx*8..+7
    const int lr = tid >> 2, lk = (tid & 3) * 8;     // A-load mapping
    const int wk = tid >> 3, wc = (tid & 7) * 16;    // W-load mapping

    float acc[4][8];
    #pragma unroll
    for (int i = 0; i < 4; ++i)
        #pragma unroll
        for (int j = 0; j < 8; ++j) acc[i][j] = 0.f;

    for (int k0 = 0; k0 < K; k0 += BK) {
        int ar = row0 + lr; if (ar >= M) ar = M - 1;
        const float* ap = A + (size_t)ar * K + k0 + lk;
        float4 a0 = ((const float4*)ap)[0];
        float4 a1 = ((const float4*)ap)[1];
        As[lk+0][lr] = a0.x; As[lk+1][lr] = a0.y; As[lk+2][lr] = a0.z; As[lk+3][lr] = a0.w;
        As[lk+4][lr] = a1.x; As[lk+5][lr] = a1.y; As[lk+6][lr] = a1.z; As[lk+7][lr] = a1.w;

        const float* wp = (wc < 64) ? (W0 + (size_t)(k0 + wk) * 64 + wc)
                                    : (W1 + (size_t)(k0 + wk) * 64 + (wc - 64));
        float4 w0 = ((const float4*)wp)[0];
        float4 w1 = ((const float4*)wp)[1];
        float4 w2 = ((const float4*)wp)[2];
        float4 w3 = ((const float4*)wp)[3];
        *(float4*)&Ws[wk][wc +  0] = w0;
        *(float4*)&Ws[wk][wc +  4] = w1;
        *(float4*)&Ws[wk][wc +  8] = w2;
        *(float4*)&Ws[wk][wc + 12] = w3;
        __syncthreads();

        #pragma unroll
        for (int k = 0; k < BK; ++k) {
            float4 a  = *(const float4*)&As[k][ry * 4];
            float4 wA = *(const float4*)&Ws[k][cx * 8];
            float4 wB = *(const float4*)&Ws[k][cx * 8 + 4];
            float av4[4] = {a.x, a.y, a.z, a.w};
            float wv[8]  = {wA.x, wA.y, wA.z, wA.w, wB.x, wB.y, wB.z, wB.w};
            #pragma unroll
            for (int i = 0; i < 4; ++i)
                #pragma unroll
                for (int j = 0; j < 8; ++j)
                    acc[i][j] = fmaf(av4[i], wv[j], acc[i][j]);
        }
        __syncthreads();
    }

    const int g0 = cx * 8;
    const int blk = (g0 < 64) ? blkA : blkB;
    const float* bias = (g0 < 64) ? b0 : b1;
    const int lc = g0 & 63;
    float bv[8];
    #pragma unroll
    for (int j = 0; j < 8; ++j) bv[j] = bias[lc + j];
    #pragma unroll
    for (int i = 0; i < 4; ++i) {
        int r = row0 + ry * 4 + i;
        if (r < M) {
            float* op = F + (size_t)r * DTOT + blk * 64 + lc;
            ((float4*)op)[0] = make_float4(acc[i][0]+bv[0], acc[i][1]+bv[1], acc[i][2]+bv[2], acc[i][3]+bv[3]);
            ((float4*)op)[1] = make_float4(acc[i][4]+bv[4], acc[i][5]+bv[5], acc[i][6]+bv[6], acc[i][7]+bv[7]);
        }
    }
}

// ---------------- X1: rows<USER = uE per branch; rows>=USER = l2norm(F) per 64-block -------
__global__ __launch_bounds__(256) void build_x1(
    const float* __restrict__ u_sh, const float* __restrict__ u_vsp, const float* __restrict__ u_tsp,
    const float* __restrict__ F, float* __restrict__ X1)
{
    const int n = blockIdx.x;
    const int tid = threadIdx.x;
    const int b = tid >> 6, k = tid & 63;
    if (n < USERN) {
        const float* u = (b < 2) ? u_sh : (b == 2 ? u_vsp : u_tsp);
        X1[(size_t)n * DTOT + tid] = u[(size_t)n * 64 + k];
    } else {
        const int it = n - USERN;
        float f = F[(size_t)it * DTOT + tid];
        float s = f * f;
        #pragma unroll
        for (int off = 32; off > 0; off >>= 1) s += __shfl_xor(s, off, 64);
        float nrm = fmaxf(sqrtf(s), 1e-12f);
        X1[(size_t)n * DTOT + tid] = f / nrm;
    }
}

// ---------------- X2: rows<USER = E1 rows; rows>=USER = iE per branch ----------------------
__global__ __launch_bounds__(256) void build_x2(
    const float* __restrict__ E1,
    const float* __restrict__ i_sh, const float* __restrict__ i_vsp, const float* __restrict__ i_tsp,
    float* __restrict__ X2)
{
    const int n = blockIdx.x;
    const int tid = threadIdx.x;
    if (n < USERN) {
        X2[(size_t)n * DTOT + tid] = E1[(size_t)n * DTOT + tid];
    } else {
        const int b = tid >> 6, k = tid & 63;
        const int it = n - USERN;
        const float* p = (b < 2) ? i_sh : (b == 2 ? i_vsp : i_tsp);
        X2[(size_t)n * DTOT + tid] = p[(size_t)it * 64 + k];
    }
}

// ---------------- main-adj SpMM, D=256, one wave per edge ----------------------------------
__global__ __launch_bounds__(256) void spmm256(
    const int* __restrict__ rows, const int* __restrict__ cols, const float* __restrict__ vals,
    int E, const float* __restrict__ X, float* __restrict__ Y)
{
    const int gtid = blockIdx.x * blockDim.x + threadIdx.x;
    const int w  = gtid >> 6;
    const int nw = (gridDim.x * blockDim.x) >> 6;
    const int lane = threadIdx.x & 63;
    for (int e = w; e < E; e += nw) {
        const int c = cols[e], r = rows[e];
        const float v = vals[e];
        float4 g = ((const float4*)(X + (size_t)c * DTOT))[lane];
        float* o = Y + (size_t)r * DTOT + (lane << 2);
        atomicAdd(o + 0, v * g.x);
        atomicAdd(o + 1, v * g.y);
        atomicAdd(o + 2, v * g.z);
        atomicAdd(o + 3, v * g.w);
    }
}

// ---------------- modal SpMM, 128 dims/edge (2 branch blocks), half-wave per edge ----------
__global__ __launch_bounds__(256) void spmm_modal(
    const int* __restrict__ rows, const int* __restrict__ cols, const float* __restrict__ vals,
    int E, const float* __restrict__ XU, const float* __restrict__ XI,
    float* __restrict__ Y, int blkOff, float scale)
{
    const int gtid = blockIdx.x * blockDim.x + threadIdx.x;
    const int h  = gtid >> 5;
    const int nh = (gridDim.x * blockDim.x) >> 5;
    const int l = threadIdx.x & 31;
    const int d = blkOff + (l >> 4) * 128 + (l & 15) * 4;
    for (int e = h; e < E; e += nh) {
        const int c = cols[e], r = rows[e];
        const float v = vals[e] * scale;
        const float* src = ((c < USERN) ? XU : XI) + (size_t)c * DTOT + d;
        float4 g = *(const float4*)src;
        float* o = Y + (size_t)r * DTOT + d;
        atomicAdd(o + 0, v * g.x);
        atomicAdd(o + 1, v * g.y);
        atomicAdd(o + 2, v * g.z);
        atomicAdd(o + 3, v * g.w);
    }
}

// ---------------- elementwise adds ---------------------------------------------------------
__global__ __launch_bounds__(256) void addA(float* __restrict__ out, const float* __restrict__ a, int n4)
{
    int i = blockIdx.x * blockDim.x + threadIdx.x;
    if (i < n4) {
        float4 o = ((float4*)out)[i];
        float4 x = ((const float4*)a)[i];
        o.x += x.x; o.y += x.y; o.z += x.z; o.w += x.w;
        ((float4*)out)[i] = o;
    }
}

__global__ __launch_bounds__(256) void addAB(float* __restrict__ out, const float* __restrict__ a,
                                             const float* __restrict__ b, int n4)
{
    int i = blockIdx.x * blockDim.x + threadIdx.x;
    if (i < n4) {
        float4 o = ((float4*)out)[i];
        float4 x = ((const float4*)a)[i];
        float4 y = ((const float4*)b)[i];
        o.x += x.x + y.x; o.y += x.y + y.y; o.z += x.z + y.z; o.w += x.w + y.w;
        ((float4*)out)[i] = o;
    }
}

extern "C" void kernel_launch(void* const* d_in, const int* in_sizes, int n_in,
                              void* d_out, int out_size, void* d_ws, size_t ws_size,
                              hipStream_t stream)
{
    const float* img = (const float*)d_in[0];
    const float* txt = (const float*)d_in[1];
    const int*   ar  = (const int*)d_in[2];
    const int*   ac  = (const int*)d_in[3];
    const float* av  = (const float*)d_in[4];
    const int*   mir = (const int*)d_in[5];
    const int*   mic = (const int*)d_in[6];
    const float* miv = (const float*)d_in[7];
    const int*   mtr = (const int*)d_in[8];
    const int*   mtc = (const int*)d_in[9];
    const float* mtv = (const float*)d_in[10];
    const float* u_sh   = (const float*)d_in[11];
    const float* i_sh   = (const float*)d_in[12];
    const float* Wi_sh  = (const float*)d_in[13];
    const float* bi_sh  = (const float*)d_in[14];
    const float* Wt_sh  = (const float*)d_in[15];
    const float* bt_sh  = (const float*)d_in[16];
    const float* u_vsp  = (const float*)d_in[17];
    const float* i_vsp  = (const float*)d_in[18];
    const float* Wi_vsp = (const float*)d_in[19];
    const float* bi_vsp = (const float*)d_in[20];
    const float* u_tsp  = (const float*)d_in[21];
    const float* i_tsp  = (const float*)d_in[22];
    const float* Wt_tsp = (const float*)d_in[23];
    const float* bt_tsp = (const float*)d_in[24];

    float* F  = (float*)d_ws;                    // [ITEM, 256]
    float* X1 = F  + (size_t)ITEMN * DTOT;       // [N, 256]
    float* X2 = X1 + (size_t)NN * DTOT;          // [N, 256]
    float* E1 = X2 + (size_t)NN * DTOT;          // [N, 256]
    float* C1 = X1;                              // reuse after modal pass
    float* C2 = X2;                              // reuse after pass2
    float* out = (float*)d_out;                  // [N, 256] = accumulator

    const size_t nbytes = (size_t)NN * DTOT * sizeof(float);
    const int n4 = NN * (DTOT / 4);

    // 1. feature projections -> F (blocks: 0=img_sh, 1=txt_sh, 2=img_sp, 3=txt_sp)
    gemm_proj<<<(ITEMN + BM - 1) / BM, 256, 0, stream>>>(img, ITEMN, 4096, Wi_sh, Wi_vsp, bi_sh, bi_vsp, F, 0, 2);
    gemm_proj<<<(ITEMN + BM - 1) / BM, 256, 0, stream>>>(txt, ITEMN,  768, Wt_sh, Wt_tsp, bt_sh, bt_tsp, F, 1, 3);

    // 2. X1 = [uE ; l2norm(feats)]
    build_x1<<<NN, 256, 0, stream>>>(u_sh, u_vsp, u_tsp, F, X1);

    // 3. pass1: E1 = adj @ X1
    hipMemsetAsync(E1, 0, nbytes, stream);
    spmm256<<<16384, 256, 0, stream>>>(ar, ac, av, E_MAINN, X1, E1);

    // 4. X2 = [E1_users ; iE]
    build_x2<<<NN, 256, 0, stream>>>(E1, i_sh, i_vsp, i_tsp, X2);

    // 5. out = LAM * (modal @ base); base users from X1, items from X2
    hipMemsetAsync(out, 0, nbytes, stream);
    spmm_modal<<<8192, 256, 0, stream>>>(mir, mic, miv, E_MODALN, X1, X2, out, 0,  LAMv); // branches 0,2
    spmm_modal<<<8192, 256, 0, stream>>>(mtr, mtc, mtv, E_MODALN, X1, X2, out, 64, LAMv); // branches 1,3

    // 6. out += adj @ X2   (pass2)
    spmm256<<<16384, 256, 0, stream>>>(ar, ac, av, E_MAINN, X2, out);

    // 7. out += E1  -> out = e_comb (= stage-0 total = cur)
    addA<<<(n4 + 255) / 256, 256, 0, stream>>>(out, E1, n4);

    // 8. GNN layer 1: C1 = adj @ out
    hipMemsetAsync(C1, 0, nbytes, stream);
    spmm256<<<16384, 256, 0, stream>>>(ar, ac, av, E_MAINN, out, C1);

    // 9. GNN layer 2: C2 = adj @ C1
    hipMemsetAsync(C2, 0, nbytes, stream);
    spmm256<<<16384, 256, 0, stream>>>(ar, ac, av, E_MAINN, C1, C2);

    // 10. out += C1 + C2
    addAB<<<(n4 + 255) / 256, 256, 0, stream>>>(out, C1, C2, n4);
}

// Round 2
// 2453.023 us; speedup vs baseline: 12.4760x; 12.4760x over previous
//
#include <hip/hip_runtime.h>

#define USERN 50000
#define ITEMN 20000
#define NN    70000
#define DTOT  256        // 4 branches x 64
#define LAMv  0.2f
#define E_MAINN  2000000
#define E_MODALN 1000000

// ---------------- dense projection GEMM: F[:,blkA*64..]=A@W0+b0, F[:,blkB*64..]=A@W1+b1 ----
#define BM 64
#define BN 128
#define BK 32

__global__ __launch_bounds__(256) void gemm_proj(
    const float* __restrict__ A, int M, int K,
    const float* __restrict__ W0, const float* __restrict__ W1,
    const float* __restrict__ b0, const float* __restrict__ b1,
    float* __restrict__ F, int blkA, int blkB)
{
    __shared__ float As[BK][BM];   // transposed A tile
    __shared__ float Ws[BK][BN];   // [k][col], cols 0-63 from W0, 64-127 from W1
    const int tid  = threadIdx.x;
    const int row0 = blockIdx.x * BM;
    const int cx = tid & 15, ry = tid >> 4;          // thread computes rows ry*4..+3, cols cx*8..+7
    const int lr = tid >> 2, lk = (tid & 3) * 8;     // A-load mapping
    const int wk = tid >> 3, wc = (tid & 7) * 16;    // W-load mapping

    float acc[4][8];
    #pragma unroll
    for (int i = 0; i < 4; ++i)
        #pragma unroll
        for (int j = 0; j < 8; ++j) acc[i][j] = 0.f;

    for (int k0 = 0; k0 < K; k0 += BK) {
        int arow = row0 + lr; if (arow >= M) arow = M - 1;
        const float* ap = A + (size_t)arow * K + k0 + lk;
        float4 a0 = ((const float4*)ap)[0];
        float4 a1 = ((const float4*)ap)[1];
        As[lk+0][lr] = a0.x; As[lk+1][lr] = a0.y; As[lk+2][lr] = a0.z; As[lk+3][lr] = a0.w;
        As[lk+4][lr] = a1.x; As[lk+5][lr] = a1.y; As[lk+6][lr] = a1.z; As[lk+7][lr] = a1.w;

        const float* wp = (wc < 64) ? (W0 + (size_t)(k0 + wk) * 64 + wc)
                                    : (W1 + (size_t)(k0 + wk) * 64 + (wc - 64));
        float4 w0 = ((const float4*)wp)[0];
        float4 w1 = ((const float4*)wp)[1];
        float4 w2 = ((const float4*)wp)[2];
        float4 w3 = ((const float4*)wp)[3];
        *(float4*)&Ws[wk][wc +  0] = w0;
        *(float4*)&Ws[wk][wc +  4] = w1;
        *(float4*)&Ws[wk][wc +  8] = w2;
        *(float4*)&Ws[wk][wc + 12] = w3;
        __syncthreads();

        #pragma unroll
        for (int k = 0; k < BK; ++k) {
            float4 a  = *(const float4*)&As[k][ry * 4];
            float4 wA = *(const float4*)&Ws[k][cx * 8];
            float4 wB = *(const float4*)&Ws[k][cx * 8 + 4];
            float av4[4] = {a.x, a.y, a.z, a.w};
            float wv[8]  = {wA.x, wA.y, wA.z, wA.w, wB.x, wB.y, wB.z, wB.w};
            #pragma unroll
            for (int i = 0; i < 4; ++i)
                #pragma unroll
                for (int j = 0; j < 8; ++j)
                    acc[i][j] = fmaf(av4[i], wv[j], acc[i][j]);
        }
        __syncthreads();
    }

    const int g0 = cx * 8;
    const int blk = (g0 < 64) ? blkA : blkB;
    const float* bias = (g0 < 64) ? b0 : b1;
    const int lc = g0 & 63;
    float bv[8];
    #pragma unroll
    for (int j = 0; j < 8; ++j) bv[j] = bias[lc + j];
    #pragma unroll
    for (int i = 0; i < 4; ++i) {
        int r = row0 + ry * 4 + i;
        if (r < M) {
            float* op = F + (size_t)r * DTOT + blk * 64 + lc;
            ((float4*)op)[0] = make_float4(acc[i][0]+bv[0], acc[i][1]+bv[1], acc[i][2]+bv[2], acc[i][3]+bv[3]);
            ((float4*)op)[1] = make_float4(acc[i][4]+bv[4], acc[i][5]+bv[5], acc[i][6]+bv[6], acc[i][7]+bv[7]);
        }
    }
}

// ---------------- CSR build: histogram, exclusive scan, scatter ----------------------------
__global__ __launch_bounds__(256) void hist3(
    const int* __restrict__ ar, const int* __restrict__ mir, const int* __restrict__ mtr,
    int* __restrict__ cntA, int* __restrict__ cntI, int* __restrict__ cntT)
{
    const int total = E_MAINN + 2 * E_MODALN;
    for (int i = blockIdx.x * blockDim.x + threadIdx.x; i < total; i += gridDim.x * blockDim.x) {
        if (i < E_MAINN)                    atomicAdd(&cntA[ar[i]], 1);
        else if (i < E_MAINN + E_MODALN)    atomicAdd(&cntI[mir[i - E_MAINN]], 1);
        else                                atomicAdd(&cntT[mtr[i - E_MAINN - E_MODALN]], 1);
    }
}

__device__ inline int wave_incl_scan64(int x, int lane) {
    #pragma unroll
    for (int off = 1; off < 64; off <<= 1) {
        int t = __shfl_up(x, off, 64);
        if (lane >= off) x += t;
    }
    return x;
}

__global__ __launch_bounds__(1024) void exscan3(
    const int* __restrict__ cntA, const int* __restrict__ cntI, const int* __restrict__ cntT,
    int* __restrict__ rpA, int* __restrict__ rpI, int* __restrict__ rpT)
{
    const int* cnt = (blockIdx.x == 0) ? cntA : (blockIdx.x == 1 ? cntI : cntT);
    int* rp        = (blockIdx.x == 0) ? rpA  : (blockIdx.x == 1 ? rpI  : rpT);
    __shared__ int wsum[16];
    const int tid = threadIdx.x, lane = tid & 63, wv = tid >> 6;
    int run = 0;
    for (int base = 0; base < NN; base += 1024) {
        int i = base + tid;
        int v = (i < NN) ? cnt[i] : 0;
        int x = wave_incl_scan64(v, lane);
        if (lane == 63) wsum[wv] = x;
        __syncthreads();
        if (wv == 0 && lane < 16) {
            int s = wsum[lane];
            #pragma unroll
            for (int off = 1; off < 16; off <<= 1) {
                int t = __shfl_up(s, off, 64);
                if (lane >= off) s += t;
            }
            wsum[lane] = s;
        }
        __syncthreads();
        int woff = (wv > 0) ? wsum[wv - 1] : 0;
        int tot  = wsum[15];
        if (i < NN) rp[i] = run + woff + x - v;
        run += tot;
        __syncthreads();
    }
    if (tid == 0) rp[NN] = run;
}

__global__ __launch_bounds__(256) void scatter3(
    const int* __restrict__ ar,  const int* __restrict__ ac,  const float* __restrict__ av,
    const int* __restrict__ mir, const int* __restrict__ mic, const float* __restrict__ miv,
    const int* __restrict__ mtr, const int* __restrict__ mtc, const float* __restrict__ mtv,
    const int* __restrict__ rpA, const int* __restrict__ rpI, const int* __restrict__ rpT,
    int* __restrict__ cntA, int* __restrict__ cntI, int* __restrict__ cntT,
    int* __restrict__ colsA, float* __restrict__ valsA,
    int* __restrict__ colsI, float* __restrict__ valsI,
    int* __restrict__ colsT, float* __restrict__ valsT)
{
    const int total = E_MAINN + 2 * E_MODALN;
    for (int i = blockIdx.x * blockDim.x + threadIdx.x; i < total; i += gridDim.x * blockDim.x) {
        if (i < E_MAINN) {
            int r = ar[i];
            int pos = rpA[r] + atomicSub(&cntA[r], 1) - 1;
            colsA[pos] = ac[i]; valsA[pos] = av[i];
        } else if (i < E_MAINN + E_MODALN) {
            int e = i - E_MAINN;
            int r = mir[e];
            int pos = rpI[r] + atomicSub(&cntI[r], 1) - 1;
            colsI[pos] = mic[e]; valsI[pos] = miv[e];
        } else {
            int e = i - E_MAINN - E_MODALN;
            int r = mtr[e];
            int pos = rpT[r] + atomicSub(&cntT[r], 1) - 1;
            colsT[pos] = mtc[e]; valsT[pos] = mtv[e];
        }
    }
}

// ---------------- X1: rows<USER = uE per branch; rows>=USER = l2norm(F) per 64-block -------
__global__ __launch_bounds__(256) void build_x1(
    const float* __restrict__ u_sh, const float* __restrict__ u_vsp, const float* __restrict__ u_tsp,
    const float* __restrict__ F, float* __restrict__ X1)
{
    const int n = blockIdx.x;
    const int tid = threadIdx.x;
    const int b = tid >> 6, k = tid & 63;
    if (n < USERN) {
        const float* u = (b < 2) ? u_sh : (b == 2 ? u_vsp : u_tsp);
        X1[(size_t)n * DTOT + tid] = u[(size_t)n * 64 + k];
    } else {
        const int it = n - USERN;
        float f = F[(size_t)it * DTOT + tid];
        float s = f * f;
        #pragma unroll
        for (int off = 32; off > 0; off >>= 1) s += __shfl_xor(s, off, 64);
        float nrm = fmaxf(sqrtf(s), 1e-12f);
        X1[(size_t)n * DTOT + tid] = f / nrm;
    }
}

// ---------------- X2: rows<USER = E1 rows; rows>=USER = iE per branch ----------------------
__global__ __launch_bounds__(256) void build_x2(
    const float* __restrict__ E1,
    const float* __restrict__ i_sh, const float* __restrict__ i_vsp, const float* __restrict__ i_tsp,
    float* __restrict__ X2)
{
    const int n = blockIdx.x;
    const int tid = threadIdx.x;
    if (n < USERN) {
        X2[(size_t)n * DTOT + tid] = E1[(size_t)n * DTOT + tid];
    } else {
        const int b = tid >> 6, k = tid & 63;
        const int it = n - USERN;
        const float* p = (b < 2) ? i_sh : (b == 2 ? i_vsp : i_tsp);
        X2[(size_t)n * DTOT + tid] = p[(size_t)it * 64 + k];
    }
}

// ---------------- CSR SpMM: one wave per row, registers accumulate, single write -----------
__global__ __launch_bounds__(256) void spmm_csr(
    const int* __restrict__ rp, const int* __restrict__ cols, const float* __restrict__ vals,
    const float* __restrict__ X, float* __restrict__ Y)
{
    const int w = (blockIdx.x * blockDim.x + threadIdx.x) >> 6;
    if (w >= NN) return;
    const int lane = threadIdx.x & 63;
    const float4* Xv = (const float4*)X;
    int e = rp[w], end = rp[w + 1];
    float4 acc = make_float4(0.f, 0.f, 0.f, 0.f);
    for (; e < end; ++e) {
        int c = cols[e]; float v = vals[e];
        float4 g = Xv[(size_t)c * 64 + lane];
        acc.x = fmaf(v, g.x, acc.x); acc.y = fmaf(v, g.y, acc.y);
        acc.z = fmaf(v, g.z, acc.z); acc.w = fmaf(v, g.w, acc.w);
    }
    ((float4*)Y)[(size_t)w * 64 + lane] = acc;
}

// ---------------- fused: out = E1 + adj@X2 + LAM*(img modal on blk0,2) + LAM*(txt on blk1,3)
__global__ __launch_bounds__(256) void fused_comb(
    const int* __restrict__ rpA, const int* __restrict__ colsA, const float* __restrict__ valsA,
    const int* __restrict__ rpI, const int* __restrict__ colsI, const float* __restrict__ valsI,
    const int* __restrict__ rpT, const int* __restrict__ colsT, const float* __restrict__ valsT,
    const float* __restrict__ X1, const float* __restrict__ X2, const float* __restrict__ E1,
    float* __restrict__ out)
{
    const int w = (blockIdx.x * blockDim.x + threadIdx.x) >> 6;
    if (w >= NN) return;
    const int lane = threadIdx.x & 63;
    const float4* X1v = (const float4*)X1;
    const float4* X2v = (const float4*)X2;
    float4 acc = ((const float4*)E1)[(size_t)w * 64 + lane];

    // main adj @ X2
    for (int e = rpA[w], end = rpA[w + 1]; e < end; ++e) {
        int c = colsA[e]; float v = valsA[e];
        float4 g = X2v[(size_t)c * 64 + lane];
        acc.x = fmaf(v, g.x, acc.x); acc.y = fmaf(v, g.y, acc.y);
        acc.z = fmaf(v, g.z, acc.z); acc.w = fmaf(v, g.w, acc.w);
    }
    // img modal: branch blocks 0,2 -> lanes with ((lane>>4)&1)==0
    const bool imgActive = ((lane >> 4) & 1) == 0;
    for (int e = rpI[w], end = rpI[w + 1]; e < end; ++e) {
        int c = colsI[e]; float v = valsI[e] * LAMv;
        if (imgActive) {
            const float4* B = (c < USERN) ? X1v : X2v;
            float4 g = B[(size_t)c * 64 + lane];
            acc.x = fmaf(v, g.x, acc.x); acc.y = fmaf(v, g.y, acc.y);
            acc.z = fmaf(v, g.z, acc.z); acc.w = fmaf(v, g.w, acc.w);
        }
    }
    // txt modal: branch blocks 1,3
    for (int e = rpT[w], end = rpT[w + 1]; e < end; ++e) {
        int c = colsT[e]; float v = valsT[e] * LAMv;
        if (!imgActive) {
            const float4* B = (c < USERN) ? X1v : X2v;
            float4 g = B[(size_t)c * 64 + lane];
            acc.x = fmaf(v, g.x, acc.x); acc.y = fmaf(v, g.y, acc.y);
            acc.z = fmaf(v, g.z, acc.z); acc.w = fmaf(v, g.w, acc.w);
        }
    }
    ((float4*)out)[(size_t)w * 64 + lane] = acc;
}

// ---------------- final: out += C1 + adj@C1 -------------------------------------------------
__global__ __launch_bounds__(256) void fused_final(
    const int* __restrict__ rpA, const int* __restrict__ colsA, const float* __restrict__ valsA,
    const float* __restrict__ C1, float* __restrict__ out)
{
    const int w = (blockIdx.x * blockDim.x + threadIdx.x) >> 6;
    if (w >= NN) return;
    const int lane = threadIdx.x & 63;
    const float4* C1v = (const float4*)C1;
    float4 acc = make_float4(0.f, 0.f, 0.f, 0.f);
    for (int e = rpA[w], end = rpA[w + 1]; e < end; ++e) {
        int c = colsA[e]; float v = valsA[e];
        float4 g = C1v[(size_t)c * 64 + lane];
        acc.x = fmaf(v, g.x, acc.x); acc.y = fmaf(v, g.y, acc.y);
        acc.z = fmaf(v, g.z, acc.z); acc.w = fmaf(v, g.w, acc.w);
    }
    float4 o  = ((float4*)out)[(size_t)w * 64 + lane];
    float4 c1 = C1v[(size_t)w * 64 + lane];
    o.x += c1.x + acc.x; o.y += c1.y + acc.y; o.z += c1.z + acc.z; o.w += c1.w + acc.w;
    ((float4*)out)[(size_t)w * 64 + lane] = o;
}

extern "C" void kernel_launch(void* const* d_in, const int* in_sizes, int n_in,
                              void* d_out, int out_size, void* d_ws, size_t ws_size,
                              hipStream_t stream)
{
    const float* img = (const float*)d_in[0];
    const float* txt = (const float*)d_in[1];
    const int*   ar  = (const int*)d_in[2];
    const int*   ac  = (const int*)d_in[3];
    const float* av  = (const float*)d_in[4];
    const int*   mir = (const int*)d_in[5];
    const int*   mic = (const int*)d_in[6];
    const float* miv = (const float*)d_in[7];
    const int*   mtr = (const int*)d_in[8];
    const int*   mtc = (const int*)d_in[9];
    const float* mtv = (const float*)d_in[10];
    const float* u_sh   = (const float*)d_in[11];
    const float* i_sh   = (const float*)d_in[12];
    const float* Wi_sh  = (const float*)d_in[13];
    const float* bi_sh  = (const float*)d_in[14];
    const float* Wt_sh  = (const float*)d_in[15];
    const float* bt_sh  = (const float*)d_in[16];
    const float* u_vsp  = (const float*)d_in[17];
    const float* i_vsp  = (const float*)d_in[18];
    const float* Wi_vsp = (const float*)d_in[19];
    const float* bi_vsp = (const float*)d_in[20];
    const float* u_tsp  = (const float*)d_in[21];
    const float* i_tsp  = (const float*)d_in[22];
    const float* Wt_tsp = (const float*)d_in[23];
    const float* bt_tsp = (const float*)d_in[24];

    // -------- workspace layout --------
    float* F  = (float*)d_ws;                    // [ITEM, 256]       20.48 MB
    float* X1 = F  + (size_t)ITEMN * DTOT;       // [N, 256]          71.68 MB
    float* X2 = X1 + (size_t)NN * DTOT;          // [N, 256]
    float* E1 = X2 + (size_t)NN * DTOT;          // [N, 256]
    int*   rpA   = (int*)(E1 + (size_t)NN * DTOT);   // N+1
    int*   rpI   = rpA + (NN + 4);
    int*   rpT   = rpI + (NN + 4);
    int*   cntA  = rpT + (NN + 4);                   // 3 x N counters (contiguous)
    int*   cntI  = cntA + NN;
    int*   cntT  = cntI + NN;
    int*   colsA = cntT + NN;                        // 2M
    float* valsA = (float*)(colsA + E_MAINN);        // 2M
    int*   colsI = (int*)(valsA + E_MAINN);          // 1M
    float* valsI = (float*)(colsI + E_MODALN);
    int*   colsT = (int*)(valsI + E_MODALN);
    float* valsT = (float*)(colsT + E_MODALN);
    float* C1 = X1;                              // reuse after fused_comb
    float* out = (float*)d_out;                  // [N, 256]

    const int waveBlocks = (NN * 64 + 255) / 256;    // one wave per row

    // -------- CSR build (all 3 graphs) --------
    hipMemsetAsync(cntA, 0, 3 * (size_t)NN * sizeof(int), stream);
    hist3<<<2048, 256, 0, stream>>>(ar, mir, mtr, cntA, cntI, cntT);
    exscan3<<<3, 1024, 0, stream>>>(cntA, cntI, cntT, rpA, rpI, rpT);
    scatter3<<<2048, 256, 0, stream>>>(ar, ac, av, mir, mic, miv, mtr, mtc, mtv,
                                       rpA, rpI, rpT, cntA, cntI, cntT,
                                       colsA, valsA, colsI, valsI, colsT, valsT);

    // -------- feature projections -> F (blocks: 0=img_sh, 1=txt_sh, 2=img_sp, 3=txt_sp) ----
    gemm_proj<<<(ITEMN + BM - 1) / BM, 256, 0, stream>>>(img, ITEMN, 4096, Wi_sh, Wi_vsp, bi_sh, bi_vsp, F, 0, 2);
    gemm_proj<<<(ITEMN + BM - 1) / BM, 256, 0, stream>>>(txt, ITEMN,  768, Wt_sh, Wt_tsp, bt_sh, bt_tsp, F, 1, 3);

    // -------- X1 = [uE ; l2norm(feats)] --------
    build_x1<<<NN, 256, 0, stream>>>(u_sh, u_vsp, u_tsp, F, X1);

    // -------- pass1: E1 = adj @ X1 --------
    spmm_csr<<<waveBlocks, 256, 0, stream>>>(rpA, colsA, valsA, X1, E1);

    // -------- X2 = [E1_users ; iE] --------
    build_x2<<<NN, 256, 0, stream>>>(E1, i_sh, i_vsp, i_tsp, X2);

    // -------- out = E1 + adj@X2 + LAM*modal --------
    fused_comb<<<waveBlocks, 256, 0, stream>>>(rpA, colsA, valsA,
                                               rpI, colsI, valsI,
                                               rpT, colsT, valsT,
                                               X1, X2, E1, out);

    // -------- GNN layer 1: C1 = adj @ out --------
    spmm_csr<<<waveBlocks, 256, 0, stream>>>(rpA, colsA, valsA, out, C1);

    // -------- GNN layer 2 + final sum: out += C1 + adj@C1 --------
    fused_final<<<waveBlocks, 256, 0, stream>>>(rpA, colsA, valsA, C1, out);
}

// Round 3
// 2232.279 us; speedup vs baseline: 13.7097x; 1.0989x over previous
//
#include <hip/hip_runtime.h>

#define USERN 50000
#define ITEMN 20000
#define NN    70000
#define DTOT  256        // 4 branches x 64
#define LAMv  0.2f
#define E_MAINN  2000000
#define E_MODALN 1000000

// ---------------- dense projection GEMM, K-split partials --------------------------------
// grid (313, 4), block 128. Each block: 64 rows x 128 cols, K-segment of K/4.
// Thread tile 8x8. P[seg][item][256]; img fills blocks 0,2; txt fills blocks 1,3.
#define BM 64
#define BN 128
#define BK 32

__global__ __launch_bounds__(128) void gemm_part(
    const float* __restrict__ A, int M, int K,
    const float* __restrict__ W0, const float* __restrict__ W1,
    float* __restrict__ P, int blkA, int blkB)
{
    __shared__ __align__(16) float As[BK][BM + 4];   // [k][row] stride 68 (272B, 16B-aligned)
    __shared__ __align__(16) float Ws[BK][BN + 4];   // [k][col] stride 132 (528B, 16B-aligned)
    const int tid  = threadIdx.x;
    const int row0 = blockIdx.x * BM;
    const int segLen = K >> 2;
    const int k0   = blockIdx.y * segLen;
    const int kend = k0 + segLen;
    float* outP = P + (size_t)blockIdx.y * ITEMN * DTOT;

    const int rg = tid >> 4;          // 0..7 -> rows rg*8..+7
    const int cx = tid & 15;          // cols cx*8..+7
    // A-load map: per chunk t: row=(tid>>3)+t*16, kk=(tid&7)*4
    const int alr = tid >> 3, alk = (tid & 7) * 4;
    // W-load map: per chunk t: wk=(tid>>5)+t*4, col=(tid&31)*4
    const int wlk = tid >> 5, wlc = (tid & 31) * 4;

    float acc[8][8];
    #pragma unroll
    for (int i = 0; i < 8; ++i)
        #pragma unroll
        for (int j = 0; j < 8; ++j) acc[i][j] = 0.f;

    for (int kt = k0; kt < kend; kt += BK) {
        // stage A tile (64 rows x 32 k), transpose-store
        #pragma unroll
        for (int t = 0; t < 4; ++t) {
            int r = row0 + alr + t * 16; if (r >= M) r = M - 1;
            float4 a = *(const float4*)(A + (size_t)r * K + kt + alk);
            As[alk + 0][alr + t * 16] = a.x;
            As[alk + 1][alr + t * 16] = a.y;
            As[alk + 2][alr + t * 16] = a.z;
            As[alk + 3][alr + t * 16] = a.w;
        }
        // stage W tile (32 k x 128 cols)
        #pragma unroll
        for (int t = 0; t < 8; ++t) {
            int wk = wlk + t * 4;
            const float* wp = (wlc < 64) ? (W0 + (size_t)(kt + wk) * 64 + wlc)
                                         : (W1 + (size_t)(kt + wk) * 64 + (wlc - 64));
            *(float4*)&Ws[wk][wlc] = *(const float4*)wp;
        }
        __syncthreads();

        #pragma unroll
        for (int k = 0; k < BK; ++k) {
            float4 a0 = *(const float4*)&As[k][rg * 8];
            float4 a1 = *(const float4*)&As[k][rg * 8 + 4];
            float4 w0 = *(const float4*)&Ws[k][cx * 8];
            float4 w1 = *(const float4*)&Ws[k][cx * 8 + 4];
            float av8[8] = {a0.x, a0.y, a0.z, a0.w, a1.x, a1.y, a1.z, a1.w};
            float wv8[8] = {w0.x, w0.y, w0.z, w0.w, w1.x, w1.y, w1.z, w1.w};
            #pragma unroll
            for (int i = 0; i < 8; ++i)
                #pragma unroll
                for (int j = 0; j < 8; ++j)
                    acc[i][j] = fmaf(av8[i], wv8[j], acc[i][j]);
        }
        __syncthreads();
    }

    const int g0  = cx * 8;
    const int blk = (g0 < 64) ? blkA : blkB;
    const int lc  = g0 & 63;
    #pragma unroll
    for (int i = 0; i < 8; ++i) {
        int r = row0 + rg * 8 + i;
        if (r < M) {
            float* op = outP + (size_t)r * DTOT + blk * 64 + lc;
            ((float4*)op)[0] = make_float4(acc[i][0], acc[i][1], acc[i][2], acc[i][3]);
            ((float4*)op)[1] = make_float4(acc[i][4], acc[i][5], acc[i][6], acc[i][7]);
        }
    }
}

// ---------------- reduce partials + bias + per-64 l2norm -> X1; user rows from uE ---------
__global__ __launch_bounds__(256) void reduce_x1(
    const float* __restrict__ P,
    const float* __restrict__ u_sh, const float* __restrict__ u_vsp, const float* __restrict__ u_tsp,
    const float* __restrict__ bi_sh, const float* __restrict__ bt_sh,
    const float* __restrict__ bi_vsp, const float* __restrict__ bt_tsp,
    float* __restrict__ X1)
{
    const int n = blockIdx.x;
    const int t = threadIdx.x;
    const int b = t >> 6, k = t & 63;
    if (n < USERN) {
        const float* u = (b < 2) ? u_sh : (b == 2 ? u_vsp : u_tsp);
        X1[(size_t)n * DTOT + t] = u[(size_t)n * 64 + k];
    } else {
        const int it = n - USERN;
        const size_t SEG = (size_t)ITEMN * DTOT;
        size_t idx = (size_t)it * DTOT + t;
        float f = P[idx] + P[idx + SEG] + P[idx + 2 * SEG] + P[idx + 3 * SEG];
        const float* bias = (b == 0) ? bi_sh : (b == 1 ? bt_sh : (b == 2 ? bi_vsp : bt_tsp));
        f += bias[k];
        float s = f * f;
        #pragma unroll
        for (int off = 32; off > 0; off >>= 1) s += __shfl_xor(s, off, 64);
        X1[(size_t)n * DTOT + t] = f / fmaxf(sqrtf(s), 1e-12f);
    }
}

// ---------------- CSR build: histogram, exclusive scan, scatter ----------------------------
__global__ __launch_bounds__(256) void hist3(
    const int* __restrict__ ar, const int* __restrict__ mir, const int* __restrict__ mtr,
    int* __restrict__ cntA, int* __restrict__ cntI, int* __restrict__ cntT)
{
    const int total = E_MAINN + 2 * E_MODALN;
    for (int i = blockIdx.x * blockDim.x + threadIdx.x; i < total; i += gridDim.x * blockDim.x) {
        if (i < E_MAINN)                    atomicAdd(&cntA[ar[i]], 1);
        else if (i < E_MAINN + E_MODALN)    atomicAdd(&cntI[mir[i - E_MAINN]], 1);
        else                                atomicAdd(&cntT[mtr[i - E_MAINN - E_MODALN]], 1);
    }
}

__device__ inline int wave_incl_scan64(int x, int lane) {
    #pragma unroll
    for (int off = 1; off < 64; off <<= 1) {
        int t = __shfl_up(x, off, 64);
        if (lane >= off) x += t;
    }
    return x;
}

__global__ __launch_bounds__(1024) void exscan3(
    const int* __restrict__ cntA, const int* __restrict__ cntI, const int* __restrict__ cntT,
    int* __restrict__ rpA, int* __restrict__ rpI, int* __restrict__ rpT)
{
    const int* cnt = (blockIdx.x == 0) ? cntA : (blockIdx.x == 1 ? cntI : cntT);
    int* rp        = (blockIdx.x == 0) ? rpA  : (blockIdx.x == 1 ? rpI  : rpT);
    __shared__ int wsum[16];
    const int tid = threadIdx.x, lane = tid & 63, wv = tid >> 6;
    int run = 0;
    for (int base = 0; base < NN; base += 1024) {
        int i = base + tid;
        int v = (i < NN) ? cnt[i] : 0;
        int x = wave_incl_scan64(v, lane);
        if (lane == 63) wsum[wv] = x;
        __syncthreads();
        if (wv == 0 && lane < 16) {
            int s = wsum[lane];
            #pragma unroll
            for (int off = 1; off < 16; off <<= 1) {
                int t = __shfl_up(s, off, 64);
                if (lane >= off) s += t;
            }
            wsum[lane] = s;
        }
        __syncthreads();
        int woff = (wv > 0) ? wsum[wv - 1] : 0;
        int tot  = wsum[15];
        if (i < NN) rp[i] = run + woff + x - v;
        run += tot;
        __syncthreads();
    }
    if (tid == 0) rp[NN] = run;
}

__global__ __launch_bounds__(256) void scatter3(
    const int* __restrict__ ar,  const int* __restrict__ ac,  const float* __restrict__ av,
    const int* __restrict__ mir, const int* __restrict__ mic, const float* __restrict__ miv,
    const int* __restrict__ mtr, const int* __restrict__ mtc, const float* __restrict__ mtv,
    const int* __restrict__ rpA, const int* __restrict__ rpI, const int* __restrict__ rpT,
    int* __restrict__ cntA, int* __restrict__ cntI, int* __restrict__ cntT,
    uint2* __restrict__ evA, uint2* __restrict__ evI, uint2* __restrict__ evT)
{
    const int total = E_MAINN + 2 * E_MODALN;
    for (int i = blockIdx.x * blockDim.x + threadIdx.x; i < total; i += gridDim.x * blockDim.x) {
        if (i < E_MAINN) {
            int r = ar[i];
            int pos = rpA[r] + atomicSub(&cntA[r], 1) - 1;
            evA[pos] = make_uint2((unsigned)ac[i], __float_as_uint(av[i]));
        } else if (i < E_MAINN + E_MODALN) {
            int e = i - E_MAINN;
            int r = mir[e];
            int pos = rpI[r] + atomicSub(&cntI[r], 1) - 1;
            evI[pos] = make_uint2((unsigned)mic[e], __float_as_uint(miv[e]));
        } else {
            int e = i - E_MAINN - E_MODALN;
            int r = mtr[e];
            int pos = rpT[r] + atomicSub(&cntT[r], 1) - 1;
            evT[pos] = make_uint2((unsigned)mtc[e], __float_as_uint(mtv[e]));
        }
    }
}

// ---------------- X2: rows<USER = E1 rows; rows>=USER = iE per branch ----------------------
__global__ __launch_bounds__(256) void build_x2(
    const float* __restrict__ E1,
    const float* __restrict__ i_sh, const float* __restrict__ i_vsp, const float* __restrict__ i_tsp,
    float* __restrict__ X2)
{
    const int n = blockIdx.x;
    const int tid = threadIdx.x;
    if (n < USERN) {
        X2[(size_t)n * DTOT + tid] = E1[(size_t)n * DTOT + tid];
    } else {
        const int b = tid >> 6, k = tid & 63;
        const int it = n - USERN;
        const float* p = (b < 2) ? i_sh : (b == 2 ? i_vsp : i_tsp);
        X2[(size_t)n * DTOT + tid] = p[(size_t)it * 64 + k];
    }
}

// ---------------- CSR SpMM, wave/row, unroll-4 gather pipeline -----------------------------
#define SPMM_BODY(ACC_INIT, WRITE)                                                  \
    const int w = (blockIdx.x * blockDim.x + threadIdx.x) >> 6;                     \
    if (w >= NN) return;                                                            \
    const int lane = threadIdx.x & 63;                                              \
    const float4* Xv = (const float4*)X;                                            \
    int e = rp[w], end = rp[w + 1];                                                 \
    float4 acc = ACC_INIT;                                                          \
    for (; e + 4 <= end; e += 4) {                                                  \
        uint2 q0 = ev[e], q1 = ev[e+1], q2 = ev[e+2], q3 = ev[e+3];                 \
        float4 g0 = Xv[(size_t)q0.x * 64 + lane];                                   \
        float4 g1 = Xv[(size_t)q1.x * 64 + lane];                                   \
        float4 g2 = Xv[(size_t)q2.x * 64 + lane];                                   \
        float4 g3 = Xv[(size_t)q3.x * 64 + lane];                                   \
        float v0 = __uint_as_float(q0.y), v1 = __uint_as_float(q1.y);               \
        float v2 = __uint_as_float(q2.y), v3 = __uint_as_float(q3.y);               \
        acc.x = fmaf(v0, g0.x, acc.x); acc.y = fmaf(v0, g0.y, acc.y);               \
        acc.z = fmaf(v0, g0.z, acc.z); acc.w = fmaf(v0, g0.w, acc.w);               \
        acc.x = fmaf(v1, g1.x, acc.x); acc.y = fmaf(v1, g1.y, acc.y);               \
        acc.z = fmaf(v1, g1.z, acc.z); acc.w = fmaf(v1, g1.w, acc.w);               \
        acc.x = fmaf(v2, g2.x, acc.x); acc.y = fmaf(v2, g2.y, acc.y);               \
        acc.z = fmaf(v2, g2.z, acc.z); acc.w = fmaf(v2, g2.w, acc.w);               \
        acc.x = fmaf(v3, g3.x, acc.x); acc.y = fmaf(v3, g3.y, acc.y);               \
        acc.z = fmaf(v3, g3.z, acc.z); acc.w = fmaf(v3, g3.w, acc.w);               \
    }                                                                               \
    for (; e < end; ++e) {                                                          \
        uint2 q = ev[e];                                                            \
        float v = __uint_as_float(q.y);                                             \
        float4 g = Xv[(size_t)q.x * 64 + lane];                                     \
        acc.x = fmaf(v, g.x, acc.x); acc.y = fmaf(v, g.y, acc.y);                   \
        acc.z = fmaf(v, g.z, acc.z); acc.w = fmaf(v, g.w, acc.w);                   \
    }                                                                               \
    WRITE

__global__ __launch_bounds__(256) void spmm_csr(
    const int* __restrict__ rp, const uint2* __restrict__ ev,
    const float* __restrict__ X, float* __restrict__ Y)
{
    SPMM_BODY(make_float4(0.f,0.f,0.f,0.f),
              ((float4*)Y)[(size_t)w * 64 + lane] = acc;)
}

// out = E1 + adj @ X2
__global__ __launch_bounds__(256) void fused_comb_main(
    const int* __restrict__ rp, const uint2* __restrict__ ev,
    const float* __restrict__ X, const float* __restrict__ E1, float* __restrict__ out)
{
    SPMM_BODY(((const float4*)E1)[(size_t)w * 64 + lane],
              ((float4*)out)[(size_t)w * 64 + lane] = acc;)
}

// out += C1 + adj @ C1
__global__ __launch_bounds__(256) void fused_final(
    const int* __restrict__ rp, const uint2* __restrict__ ev,
    const float* __restrict__ X, float* __restrict__ out)
{
    SPMM_BODY(((const float4*)X)[(size_t)w * 64 + lane],
              { float4 o = ((float4*)out)[(size_t)w * 64 + lane];
                o.x += acc.x; o.y += acc.y; o.z += acc.z; o.w += acc.w;
                ((float4*)out)[(size_t)w * 64 + lane] = o; })
}

// ---------------- modal: out += LAM * (modal @ [X1_users ; X2_items]) ----------------------
// wave -> (row, modality). 128 dims per modality = 32 float4 slots; half-waves take
// alternate edges, shfl-combine, lanes 0-31 do the RMW.
__global__ __launch_bounds__(256) void modal_add(
    const int* __restrict__ rpI, const uint2* __restrict__ evI,
    const int* __restrict__ rpT, const uint2* __restrict__ evT,
    const float* __restrict__ X1, const float* __restrict__ X2, float* __restrict__ out)
{
    const int gw = (blockIdx.x * blockDim.x + threadIdx.x) >> 6;
    if (gw >= 2 * NN) return;
    const int r = gw >> 1, m = gw & 1;
    const int lane = threadIdx.x & 63;
    const int half = lane >> 5, l5 = lane & 31;
    const int* rp      = m ? rpT : rpI;
    const uint2* ev    = m ? evT : evI;
    // float4 slot within row: blocks {m, m+2} -> slots m*16 + (l5>>4)*32 + (l5&15)
    const int d4 = m * 16 + (l5 >> 4) * 32 + (l5 & 15);
    const float4* X1v = (const float4*)X1;
    const float4* X2v = (const float4*)X2;
    float4 acc = make_float4(0.f, 0.f, 0.f, 0.f);
    const int end = rp[r + 1];
    for (int e = rp[r] + half; e < end; e += 2) {
        uint2 q = ev[e];
        float v = __uint_as_float(q.y) * LAMv;
        const float4* B = ((int)q.x < USERN) ? X1v : X2v;
        float4 g = B[(size_t)q.x * 64 + d4];
        acc.x = fmaf(v, g.x, acc.x); acc.y = fmaf(v, g.y, acc.y);
        acc.z = fmaf(v, g.z, acc.z); acc.w = fmaf(v, g.w, acc.w);
    }
    acc.x += __shfl_xor(acc.x, 32, 64);
    acc.y += __shfl_xor(acc.y, 32, 64);
    acc.z += __shfl_xor(acc.z, 32, 64);
    acc.w += __shfl_xor(acc.w, 32, 64);
    if (half == 0) {
        float4* op = (float4*)out + (size_t)r * 64 + d4;
        float4 o = *op;
        o.x += acc.x; o.y += acc.y; o.z += acc.z; o.w += acc.w;
        *op = o;
    }
}

extern "C" void kernel_launch(void* const* d_in, const int* in_sizes, int n_in,
                              void* d_out, int out_size, void* d_ws, size_t ws_size,
                              hipStream_t stream)
{
    const float* img = (const float*)d_in[0];
    const float* txt = (const float*)d_in[1];
    const int*   ar  = (const int*)d_in[2];
    const int*   ac  = (const int*)d_in[3];
    const float* av  = (const float*)d_in[4];
    const int*   mir = (const int*)d_in[5];
    const int*   mic = (const int*)d_in[6];
    const float* miv = (const float*)d_in[7];
    const int*   mtr = (const int*)d_in[8];
    const int*   mtc = (const int*)d_in[9];
    const float* mtv = (const float*)d_in[10];
    const float* u_sh   = (const float*)d_in[11];
    const float* i_sh   = (const float*)d_in[12];
    const float* Wi_sh  = (const float*)d_in[13];
    const float* bi_sh  = (const float*)d_in[14];
    const float* Wt_sh  = (const float*)d_in[15];
    const float* bt_sh  = (const float*)d_in[16];
    const float* u_vsp  = (const float*)d_in[17];
    const float* i_vsp  = (const float*)d_in[18];
    const float* Wi_vsp = (const float*)d_in[19];
    const float* bi_vsp = (const float*)d_in[20];
    const float* u_tsp  = (const float*)d_in[21];
    const float* i_tsp  = (const float*)d_in[22];
    const float* Wt_tsp = (const float*)d_in[23];
    const float* bt_tsp = (const float*)d_in[24];

    // -------- workspace layout --------
    float* X1 = (float*)d_ws;                    // [N,256]  71.68 MB
    float* X2 = X1 + (size_t)NN * DTOT;          // [N,256]  71.68 MB
    float* E1 = X2 + (size_t)NN * DTOT;          // [N,256]  71.68 MB
    float* P  = X2;                              // [4][ITEM,256] = 81.92 MB, aliases X2+part of E1
                                                 // (P dead before E1 is written, X2 built after)
    int*   rpA   = (int*)(E1 + (size_t)NN * DTOT);   // N+1
    int*   rpI   = rpA + (NN + 4);
    int*   rpT   = rpI + (NN + 4);
    int*   cntA  = rpT + (NN + 4);
    int*   cntI  = cntA + NN;
    int*   cntT  = cntI + NN;
    uint2* evA   = (uint2*)(cntT + NN);              // 2M * 8B
    uint2* evI   = evA + E_MAINN;                    // 1M * 8B
    uint2* evT   = evI + E_MODALN;                   // 1M * 8B
    float* C1  = X1;                             // reuse after modal_add
    float* out = (float*)d_out;

    const int waveBlocks  = (NN * 64) / 256;         // 17500: one wave per row
    const int modalBlocks = (2 * NN * 64) / 256;     // 35000: wave per (row, modality)

    // -------- CSR build --------
    hipMemsetAsync(cntA, 0, 3 * (size_t)NN * sizeof(int), stream);
    hist3<<<2048, 256, 0, stream>>>(ar, mir, mtr, cntA, cntI, cntT);
    exscan3<<<3, 1024, 0, stream>>>(cntA, cntI, cntT, rpA, rpI, rpT);
    scatter3<<<2048, 256, 0, stream>>>(ar, ac, av, mir, mic, miv, mtr, mtc, mtv,
                                       rpA, rpI, rpT, cntA, cntI, cntT, evA, evI, evT);

    // -------- feature projections (K-split x4 partials) --------
    gemm_part<<<dim3((ITEMN + BM - 1) / BM, 4), 128, 0, stream>>>(img, ITEMN, 4096, Wi_sh, Wi_vsp, P, 0, 2);
    gemm_part<<<dim3((ITEMN + BM - 1) / BM, 4), 128, 0, stream>>>(txt, ITEMN,  768, Wt_sh, Wt_tsp, P, 1, 3);

    // -------- X1 = [uE ; l2norm(A@W + b)] --------
    reduce_x1<<<NN, 256, 0, stream>>>(P, u_sh, u_vsp, u_tsp, bi_sh, bt_sh, bi_vsp, bt_tsp, X1);

    // -------- pass1: E1 = adj @ X1 --------
    spmm_csr<<<waveBlocks, 256, 0, stream>>>(rpA, evA, X1, E1);

    // -------- X2 = [E1_users ; iE] --------
    build_x2<<<NN, 256, 0, stream>>>(E1, i_sh, i_vsp, i_tsp, X2);

    // -------- out = E1 + adj@X2 --------
    fused_comb_main<<<waveBlocks, 256, 0, stream>>>(rpA, evA, X2, E1, out);

    // -------- out += LAM * modal --------
    modal_add<<<modalBlocks, 256, 0, stream>>>(rpI, evI, rpT, evT, X1, X2, out);

    // -------- GNN layer 1: C1 = adj @ out --------
    spmm_csr<<<waveBlocks, 256, 0, stream>>>(rpA, evA, out, C1);

    // -------- GNN layer 2 + final: out += C1 + adj@C1 --------
    fused_final<<<waveBlocks, 256, 0, stream>>>(rpA, evA, C1, out);
}

// Round 5
// 1373.939 us; speedup vs baseline: 22.2746x; 1.6247x over previous
//
#include <hip/hip_runtime.h>

#define USERN 50000
#define ITEMN 20000
#define NN    70000
#define DTOT  256        // 4 branches x 64
#define LAMv  0.2f
#define E_MAINN  2000000
#define E_MODALN 1000000

typedef float  v4f  __attribute__((ext_vector_type(4)));
typedef short  v8s  __attribute__((ext_vector_type(8)));

// ---------- bf16 helpers ----------
__device__ inline unsigned short f2bf(float f) {           // RNE
    unsigned u = __float_as_uint(f);
    u += 0x7FFFu + ((u >> 16) & 1u);
    return (unsigned short)(u >> 16);
}
__device__ inline float4 bf4f(ushort4 u) {
    float4 f;
    f.x = __uint_as_float((unsigned)u.x << 16);
    f.y = __uint_as_float((unsigned)u.y << 16);
    f.z = __uint_as_float((unsigned)u.z << 16);
    f.w = __uint_as_float((unsigned)u.w << 16);
    return f;
}
__device__ inline ushort4 f4bf(float4 f) {
    return make_ushort4(f2bf(f.x), f2bf(f.y), f2bf(f.z), f2bf(f.w));
}

// ---------------- W transpose+cvt: Wtb[c][k], c<64 from W0 else W1 -------------------------
__global__ __launch_bounds__(256) void wt_build(
    const float* __restrict__ W0, const float* __restrict__ W1, int K,
    unsigned short* __restrict__ Wtb)
{
    int idx = blockIdx.x * 256 + threadIdx.x;
    if (idx >= 128 * K) return;
    int c = idx / K, k = idx - c * K;
    float v = (c < 64) ? W0[(size_t)k * 64 + c] : W1[(size_t)k * 64 + (c - 64)];
    Wtb[idx] = f2bf(v);
}

// ---------------- MFMA GEMM: P[seg][M][256] partials, K-split x2 ---------------------------
// block 256 (4 waves), tile 64 rows x 128 cols. A f32->bf16 staged, W from Wtb (bf16).
#define LDK 40   // padded k-stride in LDS (80B rows -> conflict-free b128)

__global__ __launch_bounds__(256) void gemm_mfma(
    const float* __restrict__ A, int M, int K,
    const unsigned short* __restrict__ Wtb,
    float* __restrict__ P, int blkA, int blkB)
{
    __shared__ __align__(16) unsigned short As[64 * LDK];
    __shared__ __align__(16) unsigned short Ws[128 * LDK];
    const int tid  = threadIdx.x;
    const int row0 = blockIdx.x * 64;
    const int segLen = K >> 1;
    const int k0   = blockIdx.y * segLen;
    const int kend = k0 + segLen;
    float* outP = P + (size_t)blockIdx.y * ITEMN * DTOT;

    const int w   = tid >> 6;          // wave 0..3 -> rows w*16..
    const int l   = tid & 63;
    const int l16 = l & 15, kg = l >> 4;

    // A-stage map: thread t -> row t>>2, k-offset (t&3)*8   (4 thr x 8 = 32 k)
    const int sar = tid >> 2, sak = (tid & 3) * 8;
    // W-stage map: thread t -> col t>>1, k-offset (t&1)*16, stages 16 shorts (2 x uint4)
    const int swc = tid >> 1, swk = (tid & 1) * 16;

    v4f acc[8];
    #pragma unroll
    for (int n = 0; n < 8; ++n) acc[n] = (v4f)0.f;

    for (int kt = k0; kt < kend; kt += 32) {
        __syncthreads();
        {   // stage A: 64 rows x 32 k, f32 -> bf16
            int arow = row0 + sar; if (arow >= M) arow = M - 1;
            const float* ap = A + (size_t)arow * K + kt + sak;
            float4 a0 = ((const float4*)ap)[0];
            float4 a1 = ((const float4*)ap)[1];
            ushort4 u0 = f4bf(a0), u1 = f4bf(a1);
            *(ushort4*)&As[sar * LDK + sak]     = u0;
            *(ushort4*)&As[sar * LDK + sak + 4] = u1;
            // stage W: 128 cols x 32 k from Wtb (already bf16, [c][k]); 16 shorts/thread
            const unsigned short* wp = Wtb + (size_t)swc * K + kt + swk;
            *(uint4*)&Ws[swc * LDK + swk]     = ((const uint4*)wp)[0];
            *(uint4*)&Ws[swc * LDK + swk + 8] = ((const uint4*)wp)[1];
        }
        __syncthreads();

        v8s af = *(const v8s*)&As[(w * 16 + l16) * LDK + kg * 8];
        #pragma unroll
        for (int n = 0; n < 8; ++n) {
            v8s bf = *(const v8s*)&Ws[(n * 16 + l16) * LDK + kg * 8];
            acc[n] = __builtin_amdgcn_mfma_f32_16x16x32_bf16(af, bf, acc[n], 0, 0, 0);
        }
    }

    // D layout: col = l&15, row = (l>>4)*4 + r
    #pragma unroll
    for (int n = 0; n < 8; ++n) {
        const int col  = n * 16 + l16;
        const int gcol = (col < 64) ? blkA * 64 + col : blkB * 64 + (col - 64);
        #pragma unroll
        for (int r = 0; r < 4; ++r) {
            int row = row0 + w * 16 + kg * 4 + r;
            if (row < M) outP[(size_t)row * DTOT + gcol] = acc[n][r];
        }
    }
}

// ---------------- reduce partials + bias + per-64 l2norm -> X1b (bf16) ---------------------
__global__ __launch_bounds__(256) void reduce_x1(
    const float* __restrict__ P,
    const float* __restrict__ u_sh, const float* __restrict__ u_vsp, const float* __restrict__ u_tsp,
    const float* __restrict__ bi_sh, const float* __restrict__ bt_sh,
    const float* __restrict__ bi_vsp, const float* __restrict__ bt_tsp,
    unsigned short* __restrict__ X1b)
{
    const int n = blockIdx.x;
    const int t = threadIdx.x;
    const int b = t >> 6, k = t & 63;
    if (n < USERN) {
        const float* u = (b < 2) ? u_sh : (b == 2 ? u_vsp : u_tsp);
        X1b[(size_t)n * DTOT + t] = f2bf(u[(size_t)n * 64 + k]);
    } else {
        const int it = n - USERN;
        const size_t SEG = (size_t)ITEMN * DTOT;
        size_t idx = (size_t)it * DTOT + t;
        float f = P[idx] + P[idx + SEG];
        const float* bias = (b == 0) ? bi_sh : (b == 1 ? bt_sh : (b == 2 ? bi_vsp : bt_tsp));
        f += bias[k];
        float s = f * f;
        #pragma unroll
        for (int off = 32; off > 0; off >>= 1) s += __shfl_xor(s, off, 64);
        X1b[(size_t)n * DTOT + t] = f2bf(f / fmaxf(sqrtf(s), 1e-12f));
    }
}

// ---------------- CSR build: histogram, exclusive scan, scatter ----------------------------
__global__ __launch_bounds__(256) void hist3(
    const int* __restrict__ ar, const int* __restrict__ mir, const int* __restrict__ mtr,
    int* __restrict__ cntA, int* __restrict__ cntI, int* __restrict__ cntT)
{
    const int total = E_MAINN + 2 * E_MODALN;
    for (int i = blockIdx.x * blockDim.x + threadIdx.x; i < total; i += gridDim.x * blockDim.x) {
        if (i < E_MAINN)                    atomicAdd(&cntA[ar[i]], 1);
        else if (i < E_MAINN + E_MODALN)    atomicAdd(&cntI[mir[i - E_MAINN]], 1);
        else                                atomicAdd(&cntT[mtr[i - E_MAINN - E_MODALN]], 1);
    }
}

__device__ inline int wave_incl_scan64(int x, int lane) {
    #pragma unroll
    for (int off = 1; off < 64; off <<= 1) {
        int t = __shfl_up(x, off, 64);
        if (lane >= off) x += t;
    }
    return x;
}

__global__ __launch_bounds__(1024) void exscan3(
    const int* __restrict__ cntA, const int* __restrict__ cntI, const int* __restrict__ cntT,
    int* __restrict__ rpA, int* __restrict__ rpI, int* __restrict__ rpT)
{
    const int* cnt = (blockIdx.x == 0) ? cntA : (blockIdx.x == 1 ? cntI : cntT);
    int* rp        = (blockIdx.x == 0) ? rpA  : (blockIdx.x == 1 ? rpI  : rpT);
    __shared__ int wsum[16];
    const int tid = threadIdx.x, lane = tid & 63, wv = tid >> 6;
    int run = 0;
    for (int base = 0; base < NN; base += 1024) {
        int i = base + tid;
        int v = (i < NN) ? cnt[i] : 0;
        int x = wave_incl_scan64(v, lane);
        if (lane == 63) wsum[wv] = x;
        __syncthreads();
        if (wv == 0 && lane < 16) {
            int s = wsum[lane];
            #pragma unroll
            for (int off = 1; off < 16; off <<= 1) {
                int t = __shfl_up(s, off, 64);
                if (lane >= off) s += t;
            }
            wsum[lane] = s;
        }
        __syncthreads();
        int woff = (wv > 0) ? wsum[wv - 1] : 0;
        int tot  = wsum[15];
        if (i < NN) rp[i] = run + woff + x - v;
        run += tot;
        __syncthreads();
    }
    if (tid == 0) rp[NN] = run;
}

__global__ __launch_bounds__(256) void scatter3(
    const int* __restrict__ ar,  const int* __restrict__ ac,  const float* __restrict__ av,
    const int* __restrict__ mir, const int* __restrict__ mic, const float* __restrict__ miv,
    const int* __restrict__ mtr, const int* __restrict__ mtc, const float* __restrict__ mtv,
    const int* __restrict__ rpA, const int* __restrict__ rpI, const int* __restrict__ rpT,
    int* __restrict__ cntA, int* __restrict__ cntI, int* __restrict__ cntT,
    uint2* __restrict__ evA, uint2* __restrict__ evI, uint2* __restrict__ evT)
{
    const int total = E_MAINN + 2 * E_MODALN;
    for (int i = blockIdx.x * blockDim.x + threadIdx.x; i < total; i += gridDim.x * blockDim.x) {
        if (i < E_MAINN) {
            int r = ar[i];
            int pos = rpA[r] + atomicSub(&cntA[r], 1) - 1;
            evA[pos] = make_uint2((unsigned)ac[i], __float_as_uint(av[i]));
        } else if (i < E_MAINN + E_MODALN) {
            int e = i - E_MAINN;
            int r = mir[e];
            int pos = rpI[r] + atomicSub(&cntI[r], 1) - 1;
            evI[pos] = make_uint2((unsigned)mic[e], __float_as_uint(miv[e]));
        } else {
            int e = i - E_MAINN - E_MODALN;
            int r = mtr[e];
            int pos = rpT[r] + atomicSub(&cntT[r], 1) - 1;
            evT[pos] = make_uint2((unsigned)mtc[e], __float_as_uint(mtv[e]));
        }
    }
}

// ---------------- X2b: rows<USER = bf16(E1); rows>=USER = bf16(iE) -------------------------
__global__ __launch_bounds__(256) void build_x2b(
    const float* __restrict__ E1,
    const float* __restrict__ i_sh, const float* __restrict__ i_vsp, const float* __restrict__ i_tsp,
    unsigned short* __restrict__ X2b)
{
    const int n = blockIdx.x;
    const int t = threadIdx.x;
    if (n < USERN) {
        X2b[(size_t)n * DTOT + t] = f2bf(E1[(size_t)n * DTOT + t]);
    } else {
        const int b = t >> 6, k = t & 63;
        const int it = n - USERN;
        const float* p = (b < 2) ? i_sh : (b == 2 ? i_vsp : i_tsp);
        X2b[(size_t)n * DTOT + t] = f2bf(p[(size_t)it * 64 + k]);
    }
}

// ---------------- CSR SpMM, wave/row, bf16 gathers, unroll-4 -------------------------------
#define SPMM_BODY(ACC_INIT, WRITE)                                                  \
    const int w = (blockIdx.x * blockDim.x + threadIdx.x) >> 6;                     \
    if (w >= NN) return;                                                            \
    const int lane = threadIdx.x & 63;                                              \
    const ushort4* Xv = (const ushort4*)Xb;                                         \
    int e = rp[w], end = rp[w + 1];                                                 \
    float4 acc = ACC_INIT;                                                          \
    for (; e + 4 <= end; e += 4) {                                                  \
        uint2 q0 = ev[e], q1 = ev[e+1], q2 = ev[e+2], q3 = ev[e+3];                 \
        float4 g0 = bf4f(Xv[(size_t)q0.x * 64 + lane]);                             \
        float4 g1 = bf4f(Xv[(size_t)q1.x * 64 + lane]);                             \
        float4 g2 = bf4f(Xv[(size_t)q2.x * 64 + lane]);                             \
        float4 g3 = bf4f(Xv[(size_t)q3.x * 64 + lane]);                             \
        float v0 = __uint_as_float(q0.y), v1 = __uint_as_float(q1.y);               \
        float v2 = __uint_as_float(q2.y), v3 = __uint_as_float(q3.y);               \
        acc.x = fmaf(v0, g0.x, acc.x); acc.y = fmaf(v0, g0.y, acc.y);               \
        acc.z = fmaf(v0, g0.z, acc.z); acc.w = fmaf(v0, g0.w, acc.w);               \
        acc.x = fmaf(v1, g1.x, acc.x); acc.y = fmaf(v1, g1.y, acc.y);               \
        acc.z = fmaf(v1, g1.z, acc.z); acc.w = fmaf(v1, g1.w, acc.w);               \
        acc.x = fmaf(v2, g2.x, acc.x); acc.y = fmaf(v2, g2.y, acc.y);               \
        acc.z = fmaf(v2, g2.z, acc.z); acc.w = fmaf(v2, g2.w, acc.w);               \
        acc.x = fmaf(v3, g3.x, acc.x); acc.y = fmaf(v3, g3.y, acc.y);               \
        acc.z = fmaf(v3, g3.z, acc.z); acc.w = fmaf(v3, g3.w, acc.w);               \
    }                                                                               \
    for (; e < end; ++e) {                                                          \
        uint2 q = ev[e];                                                            \
        float v = __uint_as_float(q.y);                                             \
        float4 g = bf4f(Xv[(size_t)q.x * 64 + lane]);                               \
        acc.x = fmaf(v, g.x, acc.x); acc.y = fmaf(v, g.y, acc.y);                   \
        acc.z = fmaf(v, g.z, acc.z); acc.w = fmaf(v, g.w, acc.w);                   \
    }                                                                               \
    WRITE

// E1 = adj @ X1b   (f32 out)
__global__ __launch_bounds__(256) void spmm_e1(
    const int* __restrict__ rp, const uint2* __restrict__ ev,
    const unsigned short* __restrict__ Xb, float* __restrict__ Y)
{
    SPMM_BODY(make_float4(0.f,0.f,0.f,0.f),
              ((float4*)Y)[(size_t)w * 64 + lane] = acc;)
}

// out = E1 + adj @ X2b
__global__ __launch_bounds__(256) void fused_comb_main(
    const int* __restrict__ rp, const uint2* __restrict__ ev,
    const unsigned short* __restrict__ Xb, const float* __restrict__ E1, float* __restrict__ out)
{
    SPMM_BODY(((const float4*)E1)[(size_t)w * 64 + lane],
              ((float4*)out)[(size_t)w * 64 + lane] = acc;)
}

// C1 = adj @ OUTb  (writes f32 + bf16 copies)
__global__ __launch_bounds__(256) void spmm_l1(
    const int* __restrict__ rp, const uint2* __restrict__ ev,
    const unsigned short* __restrict__ Xb, float* __restrict__ C1, unsigned short* __restrict__ C1b)
{
    SPMM_BODY(make_float4(0.f,0.f,0.f,0.f),
              { ((float4*)C1)[(size_t)w * 64 + lane] = acc;
                ((ushort4*)C1b)[(size_t)w * 64 + lane] = f4bf(acc); })
}

// out += C1 + adj @ C1b
__global__ __launch_bounds__(256) void fused_final(
    const int* __restrict__ rp, const uint2* __restrict__ ev,
    const unsigned short* __restrict__ Xb, const float* __restrict__ C1f, float* __restrict__ out)
{
    SPMM_BODY(((const float4*)C1f)[(size_t)w * 64 + lane],
              { float4 o = ((float4*)out)[(size_t)w * 64 + lane];
                o.x += acc.x; o.y += acc.y; o.z += acc.z; o.w += acc.w;
                ((float4*)out)[(size_t)w * 64 + lane] = o; })
}

// ---------------- modal: out += LAM * (modal @ [uE ; iE]); also emits OUTb bf16 ------------
__global__ __launch_bounds__(256) void modal_add(
    const int* __restrict__ rpI, const uint2* __restrict__ evI,
    const int* __restrict__ rpT, const uint2* __restrict__ evT,
    const unsigned short* __restrict__ X1b, const unsigned short* __restrict__ X2b,
    float* __restrict__ out, unsigned short* __restrict__ OUTb)
{
    const int gw = (blockIdx.x * blockDim.x + threadIdx.x) >> 6;
    if (gw >= 2 * NN) return;
    const int r = gw >> 1, m = gw & 1;
    const int lane = threadIdx.x & 63;
    const int half = lane >> 5, l5 = lane & 31;
    const int* rp   = m ? rpT : rpI;
    const uint2* ev = m ? evT : evI;
    const int d4 = m * 16 + (l5 >> 4) * 32 + (l5 & 15);
    const ushort4* X1v = (const ushort4*)X1b;
    const ushort4* X2v = (const ushort4*)X2b;
    float4 acc = make_float4(0.f, 0.f, 0.f, 0.f);
    const int end = rp[r + 1];
    for (int e = rp[r] + half; e < end; e += 2) {
        uint2 q = ev[e];
        float v = __uint_as_float(q.y) * LAMv;
        const ushort4* B = ((int)q.x < USERN) ? X1v : X2v;
        float4 g = bf4f(B[(size_t)q.x * 64 + d4]);
        acc.x = fmaf(v, g.x, acc.x); acc.y = fmaf(v, g.y, acc.y);
        acc.z = fmaf(v, g.z, acc.z); acc.w = fmaf(v, g.w, acc.w);
    }
    acc.x += __shfl_xor(acc.x, 32, 64);
    acc.y += __shfl_xor(acc.y, 32, 64);
    acc.z += __shfl_xor(acc.z, 32, 64);
    acc.w += __shfl_xor(acc.w, 32, 64);
    if (half == 0) {
        float4* op = (float4*)out + (size_t)r * 64 + d4;
        float4 o = *op;
        o.x += acc.x; o.y += acc.y; o.z += acc.z; o.w += acc.w;
        *op = o;
        ((ushort4*)OUTb)[(size_t)r * 64 + d4] = f4bf(o);
    }
}

extern "C" void kernel_launch(void* const* d_in, const int* in_sizes, int n_in,
                              void* d_out, int out_size, void* d_ws, size_t ws_size,
                              hipStream_t stream)
{
    const float* img = (const float*)d_in[0];
    const float* txt = (const float*)d_in[1];
    const int*   ar  = (const int*)d_in[2];
    const int*   ac  = (const int*)d_in[3];
    const float* av  = (const float*)d_in[4];
    const int*   mir = (const int*)d_in[5];
    const int*   mic = (const int*)d_in[6];
    const float* miv = (const float*)d_in[7];
    const int*   mtr = (const int*)d_in[8];
    const int*   mtc = (const int*)d_in[9];
    const float* mtv = (const float*)d_in[10];
    const float* u_sh   = (const float*)d_in[11];
    const float* i_sh   = (const float*)d_in[12];
    const float* Wi_sh  = (const float*)d_in[13];
    const float* bi_sh  = (const float*)d_in[14];
    const float* Wt_sh  = (const float*)d_in[15];
    const float* bt_sh  = (const float*)d_in[16];
    const float* u_vsp  = (const float*)d_in[17];
    const float* i_vsp  = (const float*)d_in[18];
    const float* Wi_vsp = (const float*)d_in[19];
    const float* bi_vsp = (const float*)d_in[20];
    const float* u_tsp  = (const float*)d_in[21];
    const float* i_tsp  = (const float*)d_in[22];
    const float* Wt_tsp = (const float*)d_in[23];
    const float* bt_tsp = (const float*)d_in[24];

    // -------- workspace layout --------
    const size_t NE = (size_t)NN * DTOT;             // 17.92M elems
    float*  E1   = (float*)d_ws;                     // 71.68 MB (P aliases this region)
    float*  C1   = E1 + NE;                          // 71.68 MB
    unsigned short* X1b  = (unsigned short*)(C1 + NE);   // 35.84 MB
    unsigned short* X2b  = X1b + NE;                     // 35.84 MB
    unsigned short* OUTb = X2b + NE;                     // 35.84 MB
    unsigned short* C1b  = X1b;                          // alias: X1b dead after modal_add
    unsigned short* WtbI = OUTb + NE;                    // 128*4096 bf16 = 1 MB
    unsigned short* WtbT = WtbI + 128 * 4096;            // 128*768 bf16
    int*   rpA   = (int*)(WtbT + 128 * 768);
    int*   rpI   = rpA + (NN + 4);
    int*   rpT   = rpI + (NN + 4);
    int*   cntA  = rpT + (NN + 4);
    int*   cntI  = cntA + NN;
    int*   cntT  = cntI + NN;
    uint2* evA   = (uint2*)(cntT + NN);              // 2M * 8B
    uint2* evI   = evA + E_MAINN;
    uint2* evT   = evI + E_MODALN;
    float* P     = E1;                               // [2][ITEM,256] f32 = 41 MB, dead before E1 write
    float* out   = (float*)d_out;

    const int waveBlocks  = (NN * 64) / 256;         // 17500
    const int modalBlocks = (2 * NN * 64) / 256;     // 35000

    // -------- CSR build --------
    hipMemsetAsync(cntA, 0, 3 * (size_t)NN * sizeof(int), stream);
    hist3<<<2048, 256, 0, stream>>>(ar, mir, mtr, cntA, cntI, cntT);
    exscan3<<<3, 1024, 0, stream>>>(cntA, cntI, cntT, rpA, rpI, rpT);
    scatter3<<<2048, 256, 0, stream>>>(ar, ac, av, mir, mic, miv, mtr, mtc, mtv,
                                       rpA, rpI, rpT, cntA, cntI, cntT, evA, evI, evT);

    // -------- W transpose to bf16 --------
    wt_build<<<(128 * 4096 + 255) / 256, 256, 0, stream>>>(Wi_sh, Wi_vsp, 4096, WtbI);
    wt_build<<<(128 * 768  + 255) / 256, 256, 0, stream>>>(Wt_sh, Wt_tsp,  768, WtbT);

    // -------- MFMA projections (K-split x2 partials into P) --------
    gemm_mfma<<<dim3((ITEMN + 63) / 64, 2), 256, 0, stream>>>(img, ITEMN, 4096, WtbI, P, 0, 2);
    gemm_mfma<<<dim3((ITEMN + 63) / 64, 2), 256, 0, stream>>>(txt, ITEMN,  768, WtbT, P, 1, 3);

    // -------- X1b = bf16([uE ; l2norm(A@W + b)]) --------
    reduce_x1<<<NN, 256, 0, stream>>>(P, u_sh, u_vsp, u_tsp, bi_sh, bt_sh, bi_vsp, bt_tsp, X1b);

    // -------- pass1: E1 = adj @ X1b (f32) --------
    spmm_e1<<<waveBlocks, 256, 0, stream>>>(rpA, evA, X1b, E1);

    // -------- X2b = bf16([E1_users ; iE]) --------
    build_x2b<<<NN, 256, 0, stream>>>(E1, i_sh, i_vsp, i_tsp, X2b);

    // -------- out = E1 + adj@X2b --------
    fused_comb_main<<<waveBlocks, 256, 0, stream>>>(rpA, evA, X2b, E1, out);

    // -------- out += LAM*modal; OUTb = bf16(out) --------
    modal_add<<<modalBlocks, 256, 0, stream>>>(rpI, evI, rpT, evT, X1b, X2b, out, OUTb);

    // -------- layer1: C1 = adj @ OUTb (f32 + bf16) --------
    spmm_l1<<<waveBlocks, 256, 0, stream>>>(rpA, evA, OUTb, C1, C1b);

    // -------- layer2 + final: out += C1 + adj@C1b --------
    fused_final<<<waveBlocks, 256, 0, stream>>>(rpA, evA, C1b, C1, out);
}

// Round 6
// 1271.281 us; speedup vs baseline: 24.0733x; 1.0808x over previous
//
#include <hip/hip_runtime.h>

#define USERN 50000
#define ITEMN 20000
#define NN    70000
#define DTOT  256        // 4 branches x 64
#define LAMv  0.2f
#define E_MAINN  2000000
#define E_MODALN 1000000
#define SCAN_NBLK 35     // ceil(NN / 2048)

typedef float  v4f  __attribute__((ext_vector_type(4)));
typedef float  v8f  __attribute__((ext_vector_type(8)));
typedef short  v8s  __attribute__((ext_vector_type(8)));
typedef unsigned short v8u __attribute__((ext_vector_type(8)));

// ---------- bf16 helpers ----------
__device__ inline unsigned short f2bf(float f) {           // RNE
    unsigned u = __float_as_uint(f);
    u += 0x7FFFu + ((u >> 16) & 1u);
    return (unsigned short)(u >> 16);
}
__device__ inline v8f bf8f(v8u u) {
    v8f f;
    #pragma unroll
    for (int i = 0; i < 8; ++i) f[i] = __uint_as_float((unsigned)u[i] << 16);
    return f;
}
__device__ inline v8u f8bf(v8f f) {
    v8u u;
    #pragma unroll
    for (int i = 0; i < 8; ++i) u[i] = f2bf(f[i]);
    return u;
}
__device__ inline ushort4 f4bf(float4 f) {
    return make_ushort4(f2bf(f.x), f2bf(f.y), f2bf(f.z), f2bf(f.w));
}

// ---------------- W transpose+cvt: Wtb[c][k], c<64 from W0 else W1 -------------------------
__global__ __launch_bounds__(256) void wt_build(
    const float* __restrict__ W0, const float* __restrict__ W1, int K,
    unsigned short* __restrict__ Wtb)
{
    int idx = blockIdx.x * 256 + threadIdx.x;
    if (idx >= 128 * K) return;
    int c = idx / K, k = idx - c * K;
    float v = (c < 64) ? W0[(size_t)k * 64 + c] : W1[(size_t)k * 64 + (c - 64)];
    Wtb[idx] = f2bf(v);
}

// ---------------- MFMA GEMM: P[seg][M][256] partials, K-split x2 ---------------------------
#define LDK 40   // padded k-stride in LDS (80B rows -> conflict-free b128)

__global__ __launch_bounds__(256) void gemm_mfma(
    const float* __restrict__ A, int M, int K,
    const unsigned short* __restrict__ Wtb,
    float* __restrict__ P, int blkA, int blkB)
{
    __shared__ __align__(16) unsigned short As[64 * LDK];
    __shared__ __align__(16) unsigned short Ws[128 * LDK];
    const int tid  = threadIdx.x;
    const int row0 = blockIdx.x * 64;
    const int segLen = K >> 1;
    const int k0   = blockIdx.y * segLen;
    const int kend = k0 + segLen;
    float* outP = P + (size_t)blockIdx.y * ITEMN * DTOT;

    const int w   = tid >> 6;
    const int l   = tid & 63;
    const int l16 = l & 15, kg = l >> 4;

    const int sar = tid >> 2, sak = (tid & 3) * 8;
    const int swc = tid >> 1, swk = (tid & 1) * 16;

    v4f acc[8];
    #pragma unroll
    for (int n = 0; n < 8; ++n) acc[n] = (v4f)0.f;

    for (int kt = k0; kt < kend; kt += 32) {
        __syncthreads();
        {
            int arow = row0 + sar; if (arow >= M) arow = M - 1;
            const float* ap = A + (size_t)arow * K + kt + sak;
            float4 a0 = ((const float4*)ap)[0];
            float4 a1 = ((const float4*)ap)[1];
            *(ushort4*)&As[sar * LDK + sak]     = f4bf(a0);
            *(ushort4*)&As[sar * LDK + sak + 4] = f4bf(a1);
            const unsigned short* wp = Wtb + (size_t)swc * K + kt + swk;
            *(uint4*)&Ws[swc * LDK + swk]     = ((const uint4*)wp)[0];
            *(uint4*)&Ws[swc * LDK + swk + 8] = ((const uint4*)wp)[1];
        }
        __syncthreads();

        v8s af = *(const v8s*)&As[(w * 16 + l16) * LDK + kg * 8];
        #pragma unroll
        for (int n = 0; n < 8; ++n) {
            v8s bf = *(const v8s*)&Ws[(n * 16 + l16) * LDK + kg * 8];
            acc[n] = __builtin_amdgcn_mfma_f32_16x16x32_bf16(af, bf, acc[n], 0, 0, 0);
        }
    }

    #pragma unroll
    for (int n = 0; n < 8; ++n) {
        const int col  = n * 16 + l16;
        const int gcol = (col < 64) ? blkA * 64 + col : blkB * 64 + (col - 64);
        #pragma unroll
        for (int r = 0; r < 4; ++r) {
            int row = row0 + w * 16 + kg * 4 + r;
            if (row < M) outP[(size_t)row * DTOT + gcol] = acc[n][r];
        }
    }
}

// ------- build feats: X1b user=uE, item=l2norm(P-reduce+bias); X2b item=iE ----------------
__global__ __launch_bounds__(256) void build_feats(
    const float* __restrict__ P,
    const float* __restrict__ u_sh, const float* __restrict__ u_vsp, const float* __restrict__ u_tsp,
    const float* __restrict__ i_sh, const float* __restrict__ i_vsp, const float* __restrict__ i_tsp,
    const float* __restrict__ bi_sh, const float* __restrict__ bt_sh,
    const float* __restrict__ bi_vsp, const float* __restrict__ bt_tsp,
    unsigned short* __restrict__ X1b, unsigned short* __restrict__ X2b)
{
    const int n = blockIdx.x;
    const int t = threadIdx.x;
    const int b = t >> 6, k = t & 63;
    if (n < USERN) {
        const float* u = (b < 2) ? u_sh : (b == 2 ? u_vsp : u_tsp);
        X1b[(size_t)n * DTOT + t] = f2bf(u[(size_t)n * 64 + k]);
    } else {
        const int it = n - USERN;
        const size_t SEG = (size_t)ITEMN * DTOT;
        size_t idx = (size_t)it * DTOT + t;
        float f = P[idx] + P[idx + SEG];
        const float* bias = (b == 0) ? bi_sh : (b == 1 ? bt_sh : (b == 2 ? bi_vsp : bt_tsp));
        f += bias[k];
        float s = f * f;
        #pragma unroll
        for (int off = 32; off > 0; off >>= 1) s += __shfl_xor(s, off, 64);
        X1b[(size_t)n * DTOT + t] = f2bf(f / fmaxf(sqrtf(s), 1e-12f));
        const float* p = (b < 2) ? i_sh : (b == 2 ? i_vsp : i_tsp);
        X2b[(size_t)n * DTOT + t] = f2bf(p[(size_t)it * 64 + k]);
    }
}

// ---------------- CSR build: histogram, 2-kernel scan, scatter -----------------------------
__global__ __launch_bounds__(256) void hist3(
    const int* __restrict__ ar, const int* __restrict__ mir, const int* __restrict__ mtr,
    int* __restrict__ cntA, int* __restrict__ cntI, int* __restrict__ cntT)
{
    const int total = E_MAINN + 2 * E_MODALN;
    for (int i = blockIdx.x * blockDim.x + threadIdx.x; i < total; i += gridDim.x * blockDim.x) {
        if (i < E_MAINN)                    atomicAdd(&cntA[ar[i]], 1);
        else if (i < E_MAINN + E_MODALN)    atomicAdd(&cntI[mir[i - E_MAINN]], 1);
        else                                atomicAdd(&cntT[mtr[i - E_MAINN - E_MODALN]], 1);
    }
}

__device__ inline int wave_incl_scan64(int x, int lane) {
    #pragma unroll
    for (int off = 1; off < 64; off <<= 1) {
        int t = __shfl_up(x, off, 64);
        if (lane >= off) x += t;
    }
    return x;
}

__global__ __launch_bounds__(1024) void scan_bsum(
    const int* __restrict__ cntA, const int* __restrict__ cntI, const int* __restrict__ cntT,
    int* __restrict__ partial)
{
    const int g = blockIdx.y;
    const int* cnt = (g == 0) ? cntA : (g == 1 ? cntI : cntT);
    int i0 = blockIdx.x * 2048 + threadIdx.x;
    int i1 = i0 + 1024;
    int v = ((i0 < NN) ? cnt[i0] : 0) + ((i1 < NN) ? cnt[i1] : 0);
    __shared__ int ws[16];
    const int lane = threadIdx.x & 63, wv = threadIdx.x >> 6;
    #pragma unroll
    for (int off = 32; off > 0; off >>= 1) v += __shfl_xor(v, off, 64);
    if (lane == 0) ws[wv] = v;
    __syncthreads();
    if (threadIdx.x == 0) {
        int s = 0;
        #pragma unroll
        for (int i = 0; i < 16; ++i) s += ws[i];
        partial[g * SCAN_NBLK + blockIdx.x] = s;
    }
}

__global__ __launch_bounds__(1024) void scan_write(
    const int* __restrict__ cntA, const int* __restrict__ cntI, const int* __restrict__ cntT,
    const int* __restrict__ partial,
    int* __restrict__ rpA, int* __restrict__ rpI, int* __restrict__ rpT)
{
    const int g = blockIdx.y;
    const int* cnt = (g == 0) ? cntA : (g == 1 ? cntI : cntT);
    int* rp        = (g == 0) ? rpA  : (g == 1 ? rpI  : rpT);
    __shared__ int sbase;
    __shared__ int wsum[16];
    const int tid = threadIdx.x, lane = tid & 63, wv = tid >> 6;
    if (tid == 0) {
        int s = 0;
        for (int i = 0; i < (int)blockIdx.x; ++i) s += partial[g * SCAN_NBLK + i];
        sbase = s;
    }
    __syncthreads();
    int run = sbase;
    const int base = blockIdx.x * 2048;
    #pragma unroll
    for (int c = 0; c < 2; ++c) {
        int i = base + c * 1024 + tid;
        int v = (i < NN) ? cnt[i] : 0;
        int x = wave_incl_scan64(v, lane);
        if (lane == 63) wsum[wv] = x;
        __syncthreads();
        if (wv == 0 && lane < 16) {
            int s = wsum[lane];
            #pragma unroll
            for (int off = 1; off < 16; off <<= 1) {
                int t = __shfl_up(s, off, 64);
                if (lane >= off) s += t;
            }
            wsum[lane] = s;
        }
        __syncthreads();
        int woff = (wv > 0) ? wsum[wv - 1] : 0;
        if (i < NN)       rp[i]  = run + woff + x - v;
        else if (i == NN) rp[NN] = run + woff + x;
        run += wsum[15];
        __syncthreads();
    }
}

__global__ __launch_bounds__(256) void scatter3(
    const int* __restrict__ ar,  const int* __restrict__ ac,  const float* __restrict__ av,
    const int* __restrict__ mir, const int* __restrict__ mic, const float* __restrict__ miv,
    const int* __restrict__ mtr, const int* __restrict__ mtc, const float* __restrict__ mtv,
    const int* __restrict__ rpA, const int* __restrict__ rpI, const int* __restrict__ rpT,
    int* __restrict__ cntA, int* __restrict__ cntI, int* __restrict__ cntT,
    uint2* __restrict__ evA, uint2* __restrict__ evI, uint2* __restrict__ evT)
{
    const int total = E_MAINN + 2 * E_MODALN;
    for (int i = blockIdx.x * blockDim.x + threadIdx.x; i < total; i += gridDim.x * blockDim.x) {
        if (i < E_MAINN) {
            int r = ar[i];
            int pos = rpA[r] + atomicSub(&cntA[r], 1) - 1;
            evA[pos] = make_uint2((unsigned)ac[i], __float_as_uint(av[i]));
        } else if (i < E_MAINN + E_MODALN) {
            int e = i - E_MAINN;
            int r = mir[e];
            int pos = rpI[r] + atomicSub(&cntI[r], 1) - 1;
            evI[pos] = make_uint2((unsigned)mic[e], __float_as_uint(miv[e]));
        } else {
            int e = i - E_MAINN - E_MODALN;
            int r = mtr[e];
            int pos = rpT[r] + atomicSub(&cntT[r], 1) - 1;
            evT[pos] = make_uint2((unsigned)mtc[e], __float_as_uint(mtv[e]));
        }
    }
}

// -------- CSR SpMM: wave/row, half-wave per edge, 16B lanes, 8 edges in flight -------------
#define SPMM8_HEAD                                                                  \
    const int w = (blockIdx.x * blockDim.x + threadIdx.x) >> 6;                     \
    if (w >= NN) return;                                                            \
    const int lane = threadIdx.x & 63;                                              \
    const int half = lane >> 5, l5 = lane & 31;                                     \
    const v8u* __restrict__ Xv = (const v8u*)Xb;                                    \
    int e = rp[w]; const int end = rp[w + 1];                                       \
    v8f acc = (v8f)0.f;                                                             \
    for (; e + 8 <= end; e += 8) {                                                  \
        uint2 q0 = ev[e + half],     q1 = ev[e + 2 + half];                         \
        uint2 q2 = ev[e + 4 + half], q3 = ev[e + 6 + half];                         \
        v8f g0 = bf8f(Xv[(size_t)q0.x * 32 + l5]);                                  \
        v8f g1 = bf8f(Xv[(size_t)q1.x * 32 + l5]);                                  \
        v8f g2 = bf8f(Xv[(size_t)q2.x * 32 + l5]);                                  \
        v8f g3 = bf8f(Xv[(size_t)q3.x * 32 + l5]);                                  \
        float v0 = __uint_as_float(q0.y), v1 = __uint_as_float(q1.y);               \
        float v2 = __uint_as_float(q2.y), v3 = __uint_as_float(q3.y);               \
        _Pragma("unroll")                                                           \
        for (int i = 0; i < 8; ++i) {                                               \
            acc[i] = fmaf(v0, g0[i], acc[i]); acc[i] = fmaf(v1, g1[i], acc[i]);     \
            acc[i] = fmaf(v2, g2[i], acc[i]); acc[i] = fmaf(v3, g3[i], acc[i]);     \
        }                                                                           \
    }                                                                               \
    for (; e + 2 <= end; e += 2) {                                                  \
        uint2 q = ev[e + half];                                                     \
        v8f g = bf8f(Xv[(size_t)q.x * 32 + l5]);                                    \
        float v = __uint_as_float(q.y);                                             \
        _Pragma("unroll")                                                           \
        for (int i = 0; i < 8; ++i) acc[i] = fmaf(v, g[i], acc[i]);                 \
    }                                                                               \
    if (e < end && half == 0) {                                                     \
        uint2 q = ev[e];                                                            \
        v8f g = bf8f(Xv[(size_t)q.x * 32 + l5]);                                    \
        float v = __uint_as_float(q.y);                                             \
        _Pragma("unroll")                                                           \
        for (int i = 0; i < 8; ++i) acc[i] = fmaf(v, g[i], acc[i]);                 \
    }                                                                               \
    _Pragma("unroll")                                                               \
    for (int i = 0; i < 8; ++i) acc[i] += __shfl_xor(acc[i], 32, 64);               \
    if (half != 0) return;                                                          \
    const size_t oidx = (size_t)w * DTOT + l5 * 8;

// E1 = adj @ X1b; also X2b user rows = bf16(E1)
__global__ __launch_bounds__(256) void spmm_e1(
    const int* __restrict__ rp, const uint2* __restrict__ ev,
    const unsigned short* __restrict__ Xb, float* __restrict__ E1,
    unsigned short* __restrict__ X2b)
{
    SPMM8_HEAD
    *(v8f*)&E1[oidx] = acc;
    if (w < USERN) *(v8u*)&X2b[oidx] = f8bf(acc);
}

// out = E1 + adj @ X2b
__global__ __launch_bounds__(256) void fused_comb_main(
    const int* __restrict__ rp, const uint2* __restrict__ ev,
    const unsigned short* __restrict__ Xb, const float* __restrict__ E1, float* __restrict__ out)
{
    SPMM8_HEAD
    v8f o = *(const v8f*)&E1[oidx];
    #pragma unroll
    for (int i = 0; i < 8; ++i) o[i] += acc[i];
    *(v8f*)&out[oidx] = o;
}

// C1 = adj @ OUTb (f32 + bf16 copies)
__global__ __launch_bounds__(256) void spmm_l1(
    const int* __restrict__ rp, const uint2* __restrict__ ev,
    const unsigned short* __restrict__ Xb, float* __restrict__ C1, unsigned short* __restrict__ C1b)
{
    SPMM8_HEAD
    *(v8f*)&C1[oidx] = acc;
    *(v8u*)&C1b[oidx] = f8bf(acc);
}

// out += C1 + adj @ C1b
__global__ __launch_bounds__(256) void fused_final(
    const int* __restrict__ rp, const uint2* __restrict__ ev,
    const unsigned short* __restrict__ Xb, const float* __restrict__ C1f, float* __restrict__ out)
{
    SPMM8_HEAD
    v8f o = *(const v8f*)&out[oidx];
    v8f c = *(const v8f*)&C1f[oidx];
    #pragma unroll
    for (int i = 0; i < 8; ++i) o[i] += c[i] + acc[i];
    *(v8f*)&out[oidx] = o;
}

// -------- modal: wave per (row, modality), quarter-wave per edge, 16B lanes ----------------
__global__ __launch_bounds__(256) void modal_add(
    const int* __restrict__ rpI, const uint2* __restrict__ evI,
    const int* __restrict__ rpT, const uint2* __restrict__ evT,
    const unsigned short* __restrict__ X1b, const unsigned short* __restrict__ X2b,
    float* __restrict__ out, unsigned short* __restrict__ OUTb)
{
    const int gw = (blockIdx.x * blockDim.x + threadIdx.x) >> 6;
    if (gw >= 2 * NN) return;
    const int r = gw >> 1, m = gw & 1;
    const int lane = threadIdx.x & 63;
    const int qt = lane >> 4, l4 = lane & 15;
    const int* rp   = m ? rpT : rpI;
    const uint2* ev = m ? evT : evI;
    const int slot = m * 8 + (l4 >> 3) * 16 + (l4 & 7);     // ushort8 slot (blocks m, m+2)
    const v8u* X1v = (const v8u*)X1b;
    const v8u* X2v = (const v8u*)X2b;
    v8f acc = (v8f)0.f;
    int e = rp[r]; const int end = rp[r + 1];
    for (; e + 4 <= end; e += 4) {
        uint2 q = ev[e + qt];
        const v8u* B = ((int)q.x < USERN) ? X1v : X2v;
        v8f g = bf8f(B[(size_t)q.x * 32 + slot]);
        float v = __uint_as_float(q.y) * LAMv;
        #pragma unroll
        for (int i = 0; i < 8; ++i) acc[i] = fmaf(v, g[i], acc[i]);
    }
    if (qt < end - e) {
        uint2 q = ev[e + qt];
        const v8u* B = ((int)q.x < USERN) ? X1v : X2v;
        v8f g = bf8f(B[(size_t)q.x * 32 + slot]);
        float v = __uint_as_float(q.y) * LAMv;
        #pragma unroll
        for (int i = 0; i < 8; ++i) acc[i] = fmaf(v, g[i], acc[i]);
    }
    #pragma unroll
    for (int i = 0; i < 8; ++i) {
        acc[i] += __shfl_xor(acc[i], 16, 64);
        acc[i] += __shfl_xor(acc[i], 32, 64);
    }
    if (lane < 16) {
        const size_t idx = (size_t)r * DTOT + slot * 8;
        v8f o = *(const v8f*)&out[idx];
        #pragma unroll
        for (int i = 0; i < 8; ++i) o[i] += acc[i];
        *(v8f*)&out[idx] = o;
        *(v8u*)&OUTb[idx] = f8bf(o);
    }
}

extern "C" void kernel_launch(void* const* d_in, const int* in_sizes, int n_in,
                              void* d_out, int out_size, void* d_ws, size_t ws_size,
                              hipStream_t stream)
{
    const float* img = (const float*)d_in[0];
    const float* txt = (const float*)d_in[1];
    const int*   ar  = (const int*)d_in[2];
    const int*   ac  = (const int*)d_in[3];
    const float* av  = (const float*)d_in[4];
    const int*   mir = (const int*)d_in[5];
    const int*   mic = (const int*)d_in[6];
    const float* miv = (const float*)d_in[7];
    const int*   mtr = (const int*)d_in[8];
    const int*   mtc = (const int*)d_in[9];
    const float* mtv = (const float*)d_in[10];
    const float* u_sh   = (const float*)d_in[11];
    const float* i_sh   = (const float*)d_in[12];
    const float* Wi_sh  = (const float*)d_in[13];
    const float* bi_sh  = (const float*)d_in[14];
    const float* Wt_sh  = (const float*)d_in[15];
    const float* bt_sh  = (const float*)d_in[16];
    const float* u_vsp  = (const float*)d_in[17];
    const float* i_vsp  = (const float*)d_in[18];
    const float* Wi_vsp = (const float*)d_in[19];
    const float* bi_vsp = (const float*)d_in[20];
    const float* u_tsp  = (const float*)d_in[21];
    const float* i_tsp  = (const float*)d_in[22];
    const float* Wt_tsp = (const float*)d_in[23];
    const float* bt_tsp = (const float*)d_in[24];

    // -------- workspace layout --------
    const size_t NE = (size_t)NN * DTOT;
    float*  E1   = (float*)d_ws;                         // 71.68 MB (P aliases)
    float*  C1   = E1 + NE;                              // 71.68 MB
    unsigned short* X1b  = (unsigned short*)(C1 + NE);   // 35.84 MB
    unsigned short* X2b  = X1b + NE;                     // 35.84 MB
    unsigned short* OUTb = X2b + NE;                     // 35.84 MB
    unsigned short* C1b  = X1b;                          // alias: X1b dead after modal_add
    unsigned short* WtbI = OUTb + NE;                    // 1 MB
    unsigned short* WtbT = WtbI + 128 * 4096;
    int*   rpA   = (int*)(WtbT + 128 * 768);
    int*   rpI   = rpA + (NN + 4);
    int*   rpT   = rpI + (NN + 4);
    int*   cntA  = rpT + (NN + 4);
    int*   cntI  = cntA + NN;
    int*   cntT  = cntI + NN;
    int*   partial = cntT + NN;                          // 3*35 ints
    uint2* evA   = (uint2*)(partial + 3 * SCAN_NBLK + 1);
    uint2* evI   = evA + E_MAINN;
    uint2* evT   = evI + E_MODALN;
    float* P     = E1;                                   // [2][ITEM,256] f32, dead before E1 write
    float* out   = (float*)d_out;

    const int waveBlocks  = (NN * 64) / 256;             // 17500
    const int modalBlocks = (2 * NN * 64) / 256;         // 35000

    // -------- CSR build --------
    hipMemsetAsync(cntA, 0, 3 * (size_t)NN * sizeof(int), stream);
    hist3<<<2048, 256, 0, stream>>>(ar, mir, mtr, cntA, cntI, cntT);
    scan_bsum<<<dim3(SCAN_NBLK, 3), 1024, 0, stream>>>(cntA, cntI, cntT, partial);
    scan_write<<<dim3(SCAN_NBLK, 3), 1024, 0, stream>>>(cntA, cntI, cntT, partial, rpA, rpI, rpT);
    scatter3<<<2048, 256, 0, stream>>>(ar, ac, av, mir, mic, miv, mtr, mtc, mtv,
                                       rpA, rpI, rpT, cntA, cntI, cntT, evA, evI, evT);

    // -------- W transpose to bf16 --------
    wt_build<<<(128 * 4096 + 255) / 256, 256, 0, stream>>>(Wi_sh, Wi_vsp, 4096, WtbI);
    wt_build<<<(128 * 768  + 255) / 256, 256, 0, stream>>>(Wt_sh, Wt_tsp,  768, WtbT);

    // -------- MFMA projections (K-split x2 partials into P) --------
    gemm_mfma<<<dim3((ITEMN + 63) / 64, 2), 256, 0, stream>>>(img, ITEMN, 4096, WtbI, P, 0, 2);
    gemm_mfma<<<dim3((ITEMN + 63) / 64, 2), 256, 0, stream>>>(txt, ITEMN,  768, WtbT, P, 1, 3);

    // -------- X1b = bf16([uE ; l2norm(A@W+b)]); X2b item rows = bf16(iE) --------
    build_feats<<<NN, 256, 0, stream>>>(P, u_sh, u_vsp, u_tsp, i_sh, i_vsp, i_tsp,
                                        bi_sh, bt_sh, bi_vsp, bt_tsp, X1b, X2b);

    // -------- pass1: E1 = adj @ X1b; X2b user rows = bf16(E1) --------
    spmm_e1<<<waveBlocks, 256, 0, stream>>>(rpA, evA, X1b, E1, X2b);

    // -------- out = E1 + adj@X2b --------
    fused_comb_main<<<waveBlocks, 256, 0, stream>>>(rpA, evA, X2b, E1, out);

    // -------- out += LAM*modal; OUTb = bf16(out) --------
    modal_add<<<modalBlocks, 256, 0, stream>>>(rpI, evI, rpT, evT, X1b, X2b, out, OUTb);

    // -------- layer1: C1 = adj @ OUTb (f32 + bf16) --------
    spmm_l1<<<waveBlocks, 256, 0, stream>>>(rpA, evA, OUTb, C1, C1b);

    // -------- layer2 + final: out += C1 + adj@C1b --------
    fused_final<<<waveBlocks, 256, 0, stream>>>(rpA, evA, C1b, C1, out);
}